// Round 10
// baseline (1165.882 us; speedup 1.0000x reference)
//
#include <hip/hip_runtime.h>
#include <cstddef>

#define NN 50000
#define NE 800000
#define NPAD 50176
#define SCAN_BLOCKS 196   // ceil(NN/256)
#define BN_EPS 1e-5f
#define EB 192            // edges per block in edge MLP
// agg chunk geometry: 1 wave per node, 4 nodes per block -> 12500 blocks per chunk
#define BLK_PER_CHUNK 12500

// ---------------- CSR build ----------------
__global__ __launch_bounds__(256) void k_count_int(const int* __restrict__ dst,
                                                   int* __restrict__ cnt) {
    int e = blockIdx.x * 256 + threadIdx.x;
    if (e < NE) atomicAdd(&cnt[dst[e]], 1);
}

__global__ __launch_bounds__(256) void k_bsum(const int* __restrict__ cnt,
                                              int* __restrict__ bsum) {
    __shared__ int red[4];
    int i = blockIdx.x * 256 + threadIdx.x;
    int v = (i < NN) ? cnt[i] : 0;
    #pragma unroll
    for (int off = 32; off > 0; off >>= 1) v += __shfl_down(v, off, 64);
    int lane = threadIdx.x & 63, w = threadIdx.x >> 6;
    if (lane == 0) red[w] = v;
    __syncthreads();
    if (threadIdx.x == 0) bsum[blockIdx.x] = red[0] + red[1] + red[2] + red[3];
}

__global__ __launch_bounds__(256) void k_scan_bsum(int* __restrict__ bsum) {
    __shared__ int tmp[256];
    int t = threadIdx.x;
    int v = (t < SCAN_BLOCKS) ? bsum[t] : 0;
    tmp[t] = v;
    __syncthreads();
    #pragma unroll
    for (int off = 1; off < 256; off <<= 1) {
        int u = (t >= off) ? tmp[t - off] : 0;
        __syncthreads();
        tmp[t] += u;
        __syncthreads();
    }
    if (t < SCAN_BLOCKS) bsum[t] = tmp[t] - v;  // exclusive
}

__global__ __launch_bounds__(256) void k_scan_fin(const int* __restrict__ cnt,
                                                  const int* __restrict__ bsum,
                                                  int* __restrict__ row_start,
                                                  int* __restrict__ cursor,
                                                  float* __restrict__ dsq) {
    __shared__ int tmp[256];
    int t = threadIdx.x;
    int i = blockIdx.x * 256 + t;
    int c = (i < NN) ? cnt[i] : 0;
    tmp[t] = c;
    __syncthreads();
    #pragma unroll
    for (int off = 1; off < 256; off <<= 1) {
        int u = (t >= off) ? tmp[t - off] : 0;
        __syncthreads();
        tmp[t] += u;
        __syncthreads();
    }
    int excl = tmp[t] - c + bsum[blockIdx.x];
    if (i < NN) {
        row_start[i] = excl;
        cursor[i] = excl;
        dsq[i] = rsqrtf((float)c + 1.0f);
    }
    if (i == 0) row_start[NN] = NE;
}

// fill compact CSR entries: src as ushort (NN < 65536)
__global__ __launch_bounds__(256) void k_fill(const int* __restrict__ src,
                                              const int* __restrict__ dst,
                                              int* __restrict__ cursor,
                                              unsigned short* __restrict__ pk2) {
    int e = blockIdx.x * 256 + threadIdx.x;
    if (e < NE) {
        int pos = atomicAdd(&cursor[dst[e]], 1);
        pk2[pos] = (unsigned short)src[e];
    }
}

// ---------------- fp32 tiled GEMM, 64x64 tile ----------------
// BN: fused batchnorm+relu on A-read. CIS: chunk-interleaved [N/16][M][16] output scaled by dsq[row].
template <bool BN, bool CIS>
__global__ __launch_bounds__(256) void k_gemm(const float* __restrict__ A,
                                              const float* __restrict__ B,
                                              float* __restrict__ C,
                                              int M, int K, int N,
                                              const float* __restrict__ stats,
                                              const float* __restrict__ g,
                                              const float* __restrict__ be,
                                              const float* __restrict__ dsq) {
    __shared__ float As[16][68];
    __shared__ float Bs[16][68];
    const int tid = threadIdx.x;
    const int tx = tid & 15, ty = tid >> 4;
    const int row0 = blockIdx.y * 64, col0 = blockIdx.x * 64;
    float acc[4][4] = {};

    for (int kk = 0; kk < K; kk += 16) {
        #pragma unroll
        for (int i = 0; i < 4; ++i) {
            int idx = tid + i * 256;
            int m = idx >> 4, k = idx & 15;
            int gr = row0 + m;
            float v = (gr < M) ? A[(size_t)gr * K + kk + k] : 0.0f;
            if (BN) {
                int c = kk + k;
                v = fmaxf((v - stats[c]) * stats[K + c] * g[c] + be[c], 0.0f);
            }
            As[k][m] = v;
        }
        #pragma unroll
        for (int i = 0; i < 4; ++i) {
            int idx = tid + i * 256;
            int k = idx >> 6, n = idx & 63;
            Bs[k][n] = B[(size_t)(kk + k) * N + col0 + n];
        }
        __syncthreads();
        #pragma unroll
        for (int k = 0; k < 16; ++k) {
            float4 a4 = *reinterpret_cast<const float4*>(&As[k][ty * 4]);
            float4 b4 = *reinterpret_cast<const float4*>(&Bs[k][tx * 4]);
            float av[4] = {a4.x, a4.y, a4.z, a4.w};
            float bv[4] = {b4.x, b4.y, b4.z, b4.w};
            #pragma unroll
            for (int i = 0; i < 4; ++i)
                #pragma unroll
                for (int j = 0; j < 4; ++j)
                    acc[i][j] = fmaf(av[i], bv[j], acc[i][j]);
        }
        __syncthreads();
    }
    #pragma unroll
    for (int i = 0; i < 4; ++i) {
        int gr = row0 + ty * 4 + i;
        if (gr < M) {
            float4 v = make_float4(acc[i][0], acc[i][1], acc[i][2], acc[i][3]);
            if (CIS) {
                float sc = dsq[gr];
                v.x *= sc; v.y *= sc; v.z *= sc; v.w *= sc;
                int col = col0 + tx * 4;
                float* p = C + (size_t)(col >> 4) * ((size_t)M * 16) + (size_t)gr * 16 + (col & 15);
                *reinterpret_cast<float4*>(p) = v;
            } else {
                *reinterpret_cast<float4*>(&C[(size_t)gr * N + col0 + tx * 4]) = v;
            }
        }
    }
}

// ---------------- fp32 GEMM, 128x128 tile, 8x8 micro, BK=8, CI + dsq-scaled output ----
// C layout: [N/16][M][16], values scaled by dsq[row]
__global__ __launch_bounds__(256) void k_gemm128_ci(const float* __restrict__ A,
                                                    const float* __restrict__ B,
                                                    float* __restrict__ C,
                                                    int M, int K, int N,
                                                    const float* __restrict__ dsq) {
    __shared__ float As[8][132];
    __shared__ float Bs[8][132];
    const int tid = threadIdx.x;
    const int tx = tid & 15, ty = tid >> 4;
    const int row0 = blockIdx.y * 128, col0 = blockIdx.x * 128;
    float acc[8][8] = {};

    for (int kk = 0; kk < K; kk += 8) {
        {
            int m = tid >> 1;
            int k4 = (tid & 1) * 4;
            int gr = row0 + m;
            float4 v = make_float4(0.f, 0.f, 0.f, 0.f);
            if (gr < M) v = *reinterpret_cast<const float4*>(&A[(size_t)gr * K + kk + k4]);
            As[k4 + 0][m] = v.x;
            As[k4 + 1][m] = v.y;
            As[k4 + 2][m] = v.z;
            As[k4 + 3][m] = v.w;
        }
        {
            int k = tid >> 5;
            int n = (tid & 31) * 4;
            *reinterpret_cast<float4*>(&Bs[k][n]) =
                *reinterpret_cast<const float4*>(&B[(size_t)(kk + k) * N + col0 + n]);
        }
        __syncthreads();
        #pragma unroll
        for (int k = 0; k < 8; ++k) {
            float a[8], b[8];
            *reinterpret_cast<float4*>(&a[0]) = *reinterpret_cast<const float4*>(&As[k][ty * 4]);
            *reinterpret_cast<float4*>(&a[4]) = *reinterpret_cast<const float4*>(&As[k][64 + ty * 4]);
            *reinterpret_cast<float4*>(&b[0]) = *reinterpret_cast<const float4*>(&Bs[k][tx * 4]);
            *reinterpret_cast<float4*>(&b[4]) = *reinterpret_cast<const float4*>(&Bs[k][64 + tx * 4]);
            #pragma unroll
            for (int i = 0; i < 8; ++i)
                #pragma unroll
                for (int j = 0; j < 8; ++j)
                    acc[i][j] = fmaf(a[i], b[j], acc[i][j]);
        }
        __syncthreads();
    }
    const int c0a = col0 + tx * 4;
    const int c0b = col0 + 64 + tx * 4;
    float* pa = C + (size_t)(c0a >> 4) * ((size_t)M * 16) + (c0a & 15);
    float* pb = C + (size_t)(c0b >> 4) * ((size_t)M * 16) + (c0b & 15);
    #pragma unroll
    for (int i = 0; i < 8; ++i) {
        int gr = row0 + (i < 4 ? ty * 4 + i : 64 + ty * 4 + (i - 4));
        if (gr < M) {
            float sc = dsq[gr];
            float4 v0 = make_float4(acc[i][0] * sc, acc[i][1] * sc, acc[i][2] * sc, acc[i][3] * sc);
            float4 v1 = make_float4(acc[i][4] * sc, acc[i][5] * sc, acc[i][6] * sc, acc[i][7] * sc);
            *reinterpret_cast<float4*>(pa + (size_t)gr * 16) = v0;
            *reinterpret_cast<float4*>(pb + (size_t)gr * 16) = v1;
        }
    }
}

// ---------------- chunked pure-sum aggregation ----------------
// hC: [NCHUNK][NN][16] (rows pre-scaled by dsq); out row-major [NN][DOUT]
// wave = 1 node; lane = e4*16 + cc; slot e4 walks pk2[rs+e4::4].
// out[d][chunk*16+cc] = dsq[d]*(sum_s h'[s] + h'[d]) + b
template <int DOUT, bool RELU>
__device__ __forceinline__ void agg_chunk(const float* __restrict__ hk,
                                          int chunk, int d,
                                          const int* __restrict__ row_start,
                                          const unsigned short* __restrict__ pk2,
                                          const float* __restrict__ dsq,
                                          const float* __restrict__ b,
                                          float* __restrict__ out,
                                          int lane) {
    const int e4 = lane >> 4, cc = lane & 15;
    int rs = row_start[d], re = row_start[d + 1];
    float acc = 0.0f;
    for (int j = rs + e4; j < re; j += 4) {
        int s = (int)__builtin_nontemporal_load(&pk2[j]);
        acc += hk[(size_t)s * 16 + cc];
    }
    acc += __shfl_xor(acc, 16, 64);
    acc += __shfl_xor(acc, 32, 64);
    if (lane < 16) {
        float o = fmaf(dsq[d], acc + hk[(size_t)d * 16 + cc], b[chunk * 16 + cc]);
        if (RELU) o = fmaxf(o, 0.0f);
        __builtin_nontemporal_store(o, &out[(size_t)d * DOUT + chunk * 16 + cc]);
    }
}

// D=256: 16 chunks, grid = 16*BLK_PER_CHUNK; halves keep chunk->XCD 1:1
__global__ __launch_bounds__(256) void k_agg256_v3(const float* __restrict__ hC,
                                                   const int* __restrict__ row_start,
                                                   const unsigned short* __restrict__ pk2,
                                                   const float* __restrict__ dsq,
                                                   const float* __restrict__ b,
                                                   float* __restrict__ out) {
    const int tid = threadIdx.x;
    const int wave = tid >> 6, lane = tid & 63;
    int bid = blockIdx.x;
    int half = (bid >= 8 * BLK_PER_CHUNK) ? 1 : 0;
    int r = bid - half * 8 * BLK_PER_CHUNK;
    int chunk = (r & 7) + (half << 3);
    int d = (r >> 3) * 4 + wave;
    const float* hk = hC + (size_t)chunk * ((size_t)NN * 16);
    agg_chunk<256, false>(hk, chunk, d, row_start, pk2, dsq, b, out, lane);
}

// D=64: 4 chunks, grid = 4*BLK_PER_CHUNK; chunk = bid&3 -> XCDs {c, c+4}
template <bool RELU>
__global__ __launch_bounds__(256) void k_agg64_v3(const float* __restrict__ hC,
                                                  const int* __restrict__ row_start,
                                                  const unsigned short* __restrict__ pk2,
                                                  const float* __restrict__ dsq,
                                                  const float* __restrict__ b,
                                                  float* __restrict__ out) {
    const int tid = threadIdx.x;
    const int wave = tid >> 6, lane = tid & 63;
    int bid = blockIdx.x;
    int chunk = bid & 3;
    int d = (bid >> 2) * 4 + wave;
    const float* hk = hC + (size_t)chunk * ((size_t)NN * 16);
    agg_chunk<64, RELU>(hk, chunk, d, row_start, pk2, dsq, b, out, lane);
}

// ---------------- BatchNorm stats ----------------
template <int C>
__global__ __launch_bounds__(256) void k_bn_stats(const float* __restrict__ x,
                                                  float* __restrict__ stats) {
    int c = threadIdx.x & (C - 1);
    int rstart = blockIdx.x * (256 / C) + (threadIdx.x / C);
    int rstride = gridDim.x * (256 / C);
    float s = 0.0f, ss = 0.0f;
    for (int r = rstart; r < NN; r += rstride) {
        float v = x[(size_t)r * C + c];
        s += v;
        ss += v * v;
    }
    atomicAdd(&stats[c], s);
    atomicAdd(&stats[C + c], ss);
}

__global__ __launch_bounds__(256) void k_bn_fin(float* __restrict__ stats, int C) {
    int c = threadIdx.x;
    if (c < C) {
        const float invN = 1.0f / (float)NN;
        float mean = stats[c] * invN;
        float var = stats[C + c] * invN - mean * mean;
        stats[c] = mean;
        stats[C + c] = rsqrtf(var + BN_EPS);
    }
}

// ---------------- edge MLP: block-batched, coalesced gather ----------------
__global__ __launch_bounds__(EB) void k_edge_mlp3(const float* __restrict__ A,
                                                  const float* __restrict__ B,
                                                  const int* __restrict__ src,
                                                  const int* __restrict__ dst,
                                                  const float* __restrict__ b1,
                                                  const float* __restrict__ W2,
                                                  const float* __restrict__ b2,
                                                  const float* __restrict__ W3,
                                                  const float* __restrict__ b3,
                                                  float* __restrict__ out) {
    __shared__ float h1s[EB][65];
    const int tid = threadIdx.x;
    const int w = tid >> 6, lane = tid & 63;
    const int base = blockIdx.x * EB + w * 64;

    int ee = base + lane;
    if (ee >= NE) ee = NE - 1;
    int se = src[ee];
    int de = dst[ee];
    float b1v = b1[lane];

    #pragma unroll 8
    for (int i = 0; i < 64; ++i) {
        int s = __shfl(se, i, 64);
        int d = __shfl(de, i, 64);
        float v = A[(size_t)s * 64 + lane] + B[(size_t)d * 64 + lane] + b1v;
        h1s[w * 64 + i][lane] = fmaxf(v, 0.0f);
    }
    __syncthreads();

    int e = blockIdx.x * EB + tid;
    if (e >= NE) return;

    float h2[32];
    #pragma unroll
    for (int j = 0; j < 32; ++j) h2[j] = b2[j];
    #pragma unroll
    for (int k = 0; k < 64; ++k) {
        float hk = h1s[tid][k];
        const float* wr = W2 + (size_t)k * 32;
        #pragma unroll
        for (int j = 0; j < 32; ++j) h2[j] = fmaf(hk, wr[j], h2[j]);
    }

    float o0 = b3[0], o1 = b3[1];
    #pragma unroll
    for (int k = 0; k < 32; ++k) {
        float hk = fmaxf(h2[k], 0.0f);
        o0 = fmaf(hk, W3[2 * k + 0], o0);
        o1 = fmaf(hk, W3[2 * k + 1], o1);
    }
    *reinterpret_cast<float2*>(out + (size_t)2 * e) = make_float2(o0, o1);
}

// ---------------- launch ----------------
extern "C" void kernel_launch(void* const* d_in, const int* in_sizes, int n_in,
                              void* d_out, int out_size, void* d_ws, size_t ws_size,
                              hipStream_t stream) {
    const float* x    = (const float*)d_in[0];
    const int*   ei   = (const int*)d_in[1];
    const int*   src  = ei;
    const int*   dst  = ei + NE;
    const float* W1   = (const float*)d_in[2];
    const float* b1   = (const float*)d_in[3];
    const float* g1   = (const float*)d_in[4];
    const float* be1  = (const float*)d_in[5];
    const float* W2   = (const float*)d_in[6];
    const float* b2   = (const float*)d_in[7];
    const float* g2   = (const float*)d_in[8];
    const float* be2  = (const float*)d_in[9];
    const float* W3   = (const float*)d_in[10];
    const float* b3   = (const float*)d_in[11];
    const float* We1  = (const float*)d_in[12];
    const float* bme1 = (const float*)d_in[13];
    const float* We2  = (const float*)d_in[14];
    const float* bme2 = (const float*)d_in[15];
    const float* We3  = (const float*)d_in[16];
    const float* bme3 = (const float*)d_in[17];
    float* out = (float*)d_out;
    char* ws = (char*)d_ws;

    float* dsq      = (float*)ws;                         ws += NPAD * 4;
    float* stats    = (float*)ws;                         ws += 1024 * 4;
    int*   cnt      = (int*)ws;                           ws += NPAD * 4;
    int*   cursor   = (int*)ws;                           ws += NPAD * 4;
    int*   bsum     = (int*)ws;                           ws += 256 * 4;
    int*   row_start= (int*)ws;                           ws += (NPAD + 16) * 4;
    unsigned short* pk2 = (unsigned short*)ws;            ws += (size_t)NE * 2;
    ws += 64;  // alignment pad
    float* bufH     = (float*)ws;                         ws += (size_t)NN * 256 * 4;
    float* bufO     = (float*)ws;

    const int nblkE = (NE + 255) / 256;

    // ---- CSR build + degree terms ----
    hipMemsetAsync(cnt, 0, NPAD * sizeof(int), stream);
    k_count_int<<<nblkE, 256, 0, stream>>>(dst, cnt);
    k_bsum<<<SCAN_BLOCKS, 256, 0, stream>>>(cnt, bsum);
    k_scan_bsum<<<1, 256, 0, stream>>>(bsum);
    k_scan_fin<<<SCAN_BLOCKS, 256, 0, stream>>>(cnt, bsum, row_start, cursor, dsq);
    k_fill<<<nblkE, 256, 0, stream>>>(src, dst, cursor, pk2);

    // ---- layer 1: 256 -> 256 (CI + dsq-scaled gemm), chunked agg, BN stats ----
    {
        dim3 g(2, (NN + 127) / 128);
        k_gemm128_ci<<<g, 256, 0, stream>>>(x, W1, bufH, NN, 256, 256, dsq);
    }
    k_agg256_v3<<<16 * BLK_PER_CHUNK, 256, 0, stream>>>(bufH, row_start, pk2, dsq, b1, bufO);
    hipMemsetAsync(stats, 0, 1024 * sizeof(float), stream);
    k_bn_stats<256><<<256, 256, 0, stream>>>(bufO, stats);
    k_bn_fin<<<1, 256, 0, stream>>>(stats, 256);

    // ---- layer 2: A = BN1(bufO) fused; 256 -> 64 (CI+scale); chunked agg; BN2 stats ----
    {
        dim3 g(1, (NN + 63) / 64);
        k_gemm<true, true><<<g, 256, 0, stream>>>(bufO, W2, bufH, NN, 256, 64, stats, g1, be1, dsq);
    }
    k_agg64_v3<false><<<4 * BLK_PER_CHUNK, 256, 0, stream>>>(bufH, row_start, pk2, dsq, b2, bufO);
    hipMemsetAsync(stats, 0, 1024 * sizeof(float), stream);
    k_bn_stats<64><<<256, 256, 0, stream>>>(bufO, stats);
    k_bn_fin<<<1, 256, 0, stream>>>(stats, 64);

    // ---- layer 3: A = BN2(bufO) fused; 64 -> 64 (CI+scale); chunked agg + relu ----
    {
        dim3 g(1, (NN + 63) / 64);
        k_gemm<true, true><<<g, 256, 0, stream>>>(bufO, W3, bufH, NN, 64, 64, stats, g2, be2, dsq);
    }
    k_agg64_v3<true><<<4 * BLK_PER_CHUNK, 256, 0, stream>>>(bufH, row_start, pk2, dsq, b3, bufO);

    // ---- layer 4: 64 -> 64 (CI+scale, same W3/b3, no relu) -> emb in bufO ----
    {
        dim3 g(1, (NN + 63) / 64);
        k_gemm<false, true><<<g, 256, 0, stream>>>(bufO, W3, bufH, NN, 64, 64, nullptr, nullptr, nullptr, dsq);
    }
    k_agg64_v3<false><<<4 * BLK_PER_CHUNK, 256, 0, stream>>>(bufH, row_start, pk2, dsq, b3, bufO);

    // ---- edge MLP, factored layer 1 (row-major, unscaled gemms) ----
    float* Abuf = bufH;
    float* Bbuf = bufH + (size_t)NN * 64;
    {
        dim3 g(1, (NN + 63) / 64);
        k_gemm<false, false><<<g, 256, 0, stream>>>(bufO, We1, Abuf, NN, 64, 64, nullptr, nullptr, nullptr, nullptr);
        k_gemm<false, false><<<g, 256, 0, stream>>>(bufO, We1 + (size_t)64 * 64, Bbuf, NN, 64, 64, nullptr, nullptr, nullptr, nullptr);
    }
    k_edge_mlp3<<<(NE + EB - 1) / EB, EB, 0, stream>>>(Abuf, Bbuf, src, dst, bme1, We2, bme2, We3, bme3, out);

    (void)in_sizes; (void)n_in; (void)out_size; (void)ws_size;
}

// Round 11
// 680.636 us; speedup vs baseline: 1.7129x; 1.7129x over previous
//
#include <hip/hip_runtime.h>
#include <hip/hip_bf16.h>
#include <cstddef>

#define NN 50000
#define NE 800000
#define NPAD 50176
#define SCAN_BLOCKS 196   // ceil(NN/256)
#define BN_EPS 1e-5f
#define EB 192            // edges per block in edge MLP

__device__ __forceinline__ unsigned short f2bf(float f) {
    __hip_bfloat16 h = __float2bfloat16(f);
    return *reinterpret_cast<unsigned short*>(&h);
}
__device__ __forceinline__ float bf2f(unsigned short u) {
    return __uint_as_float(((unsigned int)u) << 16);
}

// ---------------- CSR build ----------------
__global__ __launch_bounds__(256) void k_count_int(const int* __restrict__ dst,
                                                   int* __restrict__ cnt) {
    int e = blockIdx.x * 256 + threadIdx.x;
    if (e < NE) atomicAdd(&cnt[dst[e]], 1);
}

__global__ __launch_bounds__(256) void k_bsum(const int* __restrict__ cnt,
                                              int* __restrict__ bsum) {
    __shared__ int red[4];
    int i = blockIdx.x * 256 + threadIdx.x;
    int v = (i < NN) ? cnt[i] : 0;
    #pragma unroll
    for (int off = 32; off > 0; off >>= 1) v += __shfl_down(v, off, 64);
    int lane = threadIdx.x & 63, w = threadIdx.x >> 6;
    if (lane == 0) red[w] = v;
    __syncthreads();
    if (threadIdx.x == 0) bsum[blockIdx.x] = red[0] + red[1] + red[2] + red[3];
}

__global__ __launch_bounds__(256) void k_scan_bsum(int* __restrict__ bsum) {
    __shared__ int tmp[256];
    int t = threadIdx.x;
    int v = (t < SCAN_BLOCKS) ? bsum[t] : 0;
    tmp[t] = v;
    __syncthreads();
    #pragma unroll
    for (int off = 1; off < 256; off <<= 1) {
        int u = (t >= off) ? tmp[t - off] : 0;
        __syncthreads();
        tmp[t] += u;
        __syncthreads();
    }
    if (t < SCAN_BLOCKS) bsum[t] = tmp[t] - v;  // exclusive
}

__global__ __launch_bounds__(256) void k_scan_fin(const int* __restrict__ cnt,
                                                  const int* __restrict__ bsum,
                                                  int* __restrict__ row_start,
                                                  int* __restrict__ cursor,
                                                  float* __restrict__ dsq) {
    __shared__ int tmp[256];
    int t = threadIdx.x;
    int i = blockIdx.x * 256 + t;
    int c = (i < NN) ? cnt[i] : 0;
    tmp[t] = c;
    __syncthreads();
    #pragma unroll
    for (int off = 1; off < 256; off <<= 1) {
        int u = (t >= off) ? tmp[t - off] : 0;
        __syncthreads();
        tmp[t] += u;
        __syncthreads();
    }
    int excl = tmp[t] - c + bsum[blockIdx.x];
    if (i < NN) {
        row_start[i] = excl;
        cursor[i] = excl;
        dsq[i] = rsqrtf((float)c + 1.0f);
    }
    if (i == 0) row_start[NN] = NE;
}

// fill compact CSR entries: src as ushort (NN < 65536)
__global__ __launch_bounds__(256) void k_fill(const int* __restrict__ src,
                                              const int* __restrict__ dst,
                                              int* __restrict__ cursor,
                                              unsigned short* __restrict__ pk2) {
    int e = blockIdx.x * 256 + threadIdx.x;
    if (e < NE) {
        int pos = atomicAdd(&cursor[dst[e]], 1);
        pk2[pos] = (unsigned short)src[e];
    }
}

// ---------------- fp32 tiled GEMM, 64x64 tile ----------------
// BN: fused batchnorm+relu on A-read. OBF: bf16 output scaled by dsq[row]; else fp32.
template <bool BN, bool OBF>
__global__ __launch_bounds__(256) void k_gemm(const float* __restrict__ A,
                                              const float* __restrict__ B,
                                              float* __restrict__ Cf,
                                              unsigned short* __restrict__ Cb,
                                              int M, int K, int N,
                                              const float* __restrict__ stats,
                                              const float* __restrict__ g,
                                              const float* __restrict__ be,
                                              const float* __restrict__ dsq) {
    __shared__ float As[16][68];
    __shared__ float Bs[16][68];
    const int tid = threadIdx.x;
    const int tx = tid & 15, ty = tid >> 4;
    const int row0 = blockIdx.y * 64, col0 = blockIdx.x * 64;
    float acc[4][4] = {};

    for (int kk = 0; kk < K; kk += 16) {
        #pragma unroll
        for (int i = 0; i < 4; ++i) {
            int idx = tid + i * 256;
            int m = idx >> 4, k = idx & 15;
            int gr = row0 + m;
            float v = (gr < M) ? A[(size_t)gr * K + kk + k] : 0.0f;
            if (BN) {
                int c = kk + k;
                v = fmaxf((v - stats[c]) * stats[K + c] * g[c] + be[c], 0.0f);
            }
            As[k][m] = v;
        }
        #pragma unroll
        for (int i = 0; i < 4; ++i) {
            int idx = tid + i * 256;
            int k = idx >> 6, n = idx & 63;
            Bs[k][n] = B[(size_t)(kk + k) * N + col0 + n];
        }
        __syncthreads();
        #pragma unroll
        for (int k = 0; k < 16; ++k) {
            float4 a4 = *reinterpret_cast<const float4*>(&As[k][ty * 4]);
            float4 b4 = *reinterpret_cast<const float4*>(&Bs[k][tx * 4]);
            float av[4] = {a4.x, a4.y, a4.z, a4.w};
            float bv[4] = {b4.x, b4.y, b4.z, b4.w};
            #pragma unroll
            for (int i = 0; i < 4; ++i)
                #pragma unroll
                for (int j = 0; j < 4; ++j)
                    acc[i][j] = fmaf(av[i], bv[j], acc[i][j]);
        }
        __syncthreads();
    }
    #pragma unroll
    for (int i = 0; i < 4; ++i) {
        int gr = row0 + ty * 4 + i;
        if (gr < M) {
            if (OBF) {
                float sc = dsq[gr];
                ushort4 u;
                u.x = f2bf(acc[i][0] * sc);
                u.y = f2bf(acc[i][1] * sc);
                u.z = f2bf(acc[i][2] * sc);
                u.w = f2bf(acc[i][3] * sc);
                *reinterpret_cast<ushort4*>(&Cb[(size_t)gr * N + col0 + tx * 4]) = u;
            } else {
                float4 v = make_float4(acc[i][0], acc[i][1], acc[i][2], acc[i][3]);
                *reinterpret_cast<float4*>(&Cf[(size_t)gr * N + col0 + tx * 4]) = v;
            }
        }
    }
}

// ---------------- fp32 GEMM, 128x128 tile, 8x8 micro, BK=8; bf16 dsq-scaled output ----
__global__ __launch_bounds__(256) void k_gemm128_bf(const float* __restrict__ A,
                                                    const float* __restrict__ B,
                                                    unsigned short* __restrict__ Cb,
                                                    int M, int K, int N,
                                                    const float* __restrict__ dsq) {
    __shared__ float As[8][132];
    __shared__ float Bs[8][132];
    const int tid = threadIdx.x;
    const int tx = tid & 15, ty = tid >> 4;
    const int row0 = blockIdx.y * 128, col0 = blockIdx.x * 128;
    float acc[8][8] = {};

    for (int kk = 0; kk < K; kk += 8) {
        {
            int m = tid >> 1;
            int k4 = (tid & 1) * 4;
            int gr = row0 + m;
            float4 v = make_float4(0.f, 0.f, 0.f, 0.f);
            if (gr < M) v = *reinterpret_cast<const float4*>(&A[(size_t)gr * K + kk + k4]);
            As[k4 + 0][m] = v.x;
            As[k4 + 1][m] = v.y;
            As[k4 + 2][m] = v.z;
            As[k4 + 3][m] = v.w;
        }
        {
            int k = tid >> 5;
            int n = (tid & 31) * 4;
            *reinterpret_cast<float4*>(&Bs[k][n]) =
                *reinterpret_cast<const float4*>(&B[(size_t)(kk + k) * N + col0 + n]);
        }
        __syncthreads();
        #pragma unroll
        for (int k = 0; k < 8; ++k) {
            float a[8], b[8];
            *reinterpret_cast<float4*>(&a[0]) = *reinterpret_cast<const float4*>(&As[k][ty * 4]);
            *reinterpret_cast<float4*>(&a[4]) = *reinterpret_cast<const float4*>(&As[k][64 + ty * 4]);
            *reinterpret_cast<float4*>(&b[0]) = *reinterpret_cast<const float4*>(&Bs[k][tx * 4]);
            *reinterpret_cast<float4*>(&b[4]) = *reinterpret_cast<const float4*>(&Bs[k][64 + tx * 4]);
            #pragma unroll
            for (int i = 0; i < 8; ++i)
                #pragma unroll
                for (int j = 0; j < 8; ++j)
                    acc[i][j] = fmaf(a[i], b[j], acc[i][j]);
        }
        __syncthreads();
    }
    #pragma unroll
    for (int i = 0; i < 8; ++i) {
        int gr = row0 + (i < 4 ? ty * 4 + i : 64 + ty * 4 + (i - 4));
        if (gr < M) {
            float sc = dsq[gr];
            ushort4 u0, u1;
            u0.x = f2bf(acc[i][0] * sc); u0.y = f2bf(acc[i][1] * sc);
            u0.z = f2bf(acc[i][2] * sc); u0.w = f2bf(acc[i][3] * sc);
            u1.x = f2bf(acc[i][4] * sc); u1.y = f2bf(acc[i][5] * sc);
            u1.z = f2bf(acc[i][6] * sc); u1.w = f2bf(acc[i][7] * sc);
            *reinterpret_cast<ushort4*>(&Cb[(size_t)gr * N + col0 + tx * 4]) = u0;
            *reinterpret_cast<ushort4*>(&Cb[(size_t)gr * N + col0 + 64 + tx * 4]) = u1;
        }
    }
}

// ---------------- CSR aggregation, D=256, bf16 rows (pre-scaled by dsq), pure sum ----
// out[d] = dsq[d]*(sum_s h'[s] + h'[d]) + b
__global__ __launch_bounds__(256) void k_agg256_b(const unsigned short* __restrict__ hb,
                                                  const int* __restrict__ row_start,
                                                  const unsigned short* __restrict__ pk2,
                                                  const float* __restrict__ dsq,
                                                  const float* __restrict__ b,
                                                  float* __restrict__ out) {
    int d = blockIdx.x * 4 + (threadIdx.x >> 6);
    if (d >= NN) return;
    int lane = threadIdx.x & 63;
    int rs = row_start[d], re = row_start[d + 1];
    float4 acc0 = make_float4(0.f, 0.f, 0.f, 0.f);
    float4 acc1 = make_float4(0.f, 0.f, 0.f, 0.f);
    int j = rs;
    for (; j + 2 <= re; j += 2) {
        int s0 = (int)pk2[j];
        int s1 = (int)pk2[j + 1];
        ushort4 v0 = *reinterpret_cast<const ushort4*>(hb + (size_t)s0 * 256 + lane * 4);
        ushort4 v1 = *reinterpret_cast<const ushort4*>(hb + (size_t)s1 * 256 + lane * 4);
        acc0.x += bf2f(v0.x); acc0.y += bf2f(v0.y); acc0.z += bf2f(v0.z); acc0.w += bf2f(v0.w);
        acc1.x += bf2f(v1.x); acc1.y += bf2f(v1.y); acc1.z += bf2f(v1.z); acc1.w += bf2f(v1.w);
    }
    if (j < re) {
        int s0 = (int)pk2[j];
        ushort4 v0 = *reinterpret_cast<const ushort4*>(hb + (size_t)s0 * 256 + lane * 4);
        acc0.x += bf2f(v0.x); acc0.y += bf2f(v0.y); acc0.z += bf2f(v0.z); acc0.w += bf2f(v0.w);
    }
    float sd = dsq[d];
    ushort4 hv = *reinterpret_cast<const ushort4*>(hb + (size_t)d * 256 + lane * 4);
    float4 bv = *reinterpret_cast<const float4*>(b + lane * 4);
    float4 o;
    o.x = fmaf(sd, acc0.x + acc1.x + bf2f(hv.x), bv.x);
    o.y = fmaf(sd, acc0.y + acc1.y + bf2f(hv.y), bv.y);
    o.z = fmaf(sd, acc0.z + acc1.z + bf2f(hv.z), bv.z);
    o.w = fmaf(sd, acc0.w + acc1.w + bf2f(hv.w), bv.w);
    *reinterpret_cast<float4*>(out + (size_t)d * 256 + lane * 4) = o;
}

// ---------------- CSR aggregation, D=64, bf16 rows (pre-scaled), pure sum ----------------
template <bool RELU>
__global__ __launch_bounds__(256) void k_agg64_b(const unsigned short* __restrict__ hb,
                                                 const int* __restrict__ row_start,
                                                 const unsigned short* __restrict__ pk2,
                                                 const float* __restrict__ dsq,
                                                 const float* __restrict__ b,
                                                 float* __restrict__ out) {
    int d = blockIdx.x * 4 + (threadIdx.x >> 6);
    if (d >= NN) return;
    int lane = threadIdx.x & 63;
    int rs = row_start[d], re = row_start[d + 1];
    float acc0 = 0.0f, acc1 = 0.0f;
    int j = rs;
    for (; j + 2 <= re; j += 2) {
        int s0 = (int)pk2[j];
        int s1 = (int)pk2[j + 1];
        acc0 += bf2f(hb[(size_t)s0 * 64 + lane]);
        acc1 += bf2f(hb[(size_t)s1 * 64 + lane]);
    }
    if (j < re) {
        int s0 = (int)pk2[j];
        acc0 += bf2f(hb[(size_t)s0 * 64 + lane]);
    }
    float o = fmaf(dsq[d], acc0 + acc1 + bf2f(hb[(size_t)d * 64 + lane]), b[lane]);
    if (RELU) o = fmaxf(o, 0.0f);
    out[(size_t)d * 64 + lane] = o;
}

// ---------------- BatchNorm stats ----------------
template <int C>
__global__ __launch_bounds__(256) void k_bn_stats(const float* __restrict__ x,
                                                  float* __restrict__ stats) {
    int c = threadIdx.x & (C - 1);
    int rstart = blockIdx.x * (256 / C) + (threadIdx.x / C);
    int rstride = gridDim.x * (256 / C);
    float s = 0.0f, ss = 0.0f;
    for (int r = rstart; r < NN; r += rstride) {
        float v = x[(size_t)r * C + c];
        s += v;
        ss += v * v;
    }
    atomicAdd(&stats[c], s);
    atomicAdd(&stats[C + c], ss);
}

__global__ __launch_bounds__(256) void k_bn_fin(float* __restrict__ stats, int C) {
    int c = threadIdx.x;
    if (c < C) {
        const float invN = 1.0f / (float)NN;
        float mean = stats[c] * invN;
        float var = stats[C + c] * invN - mean * mean;
        stats[c] = mean;
        stats[C + c] = rsqrtf(var + BN_EPS);
    }
}

// ---------------- edge MLP: block-batched, coalesced gather ----------------
__global__ __launch_bounds__(EB) void k_edge_mlp3(const float* __restrict__ A,
                                                  const float* __restrict__ B,
                                                  const int* __restrict__ src,
                                                  const int* __restrict__ dst,
                                                  const float* __restrict__ b1,
                                                  const float* __restrict__ W2,
                                                  const float* __restrict__ b2,
                                                  const float* __restrict__ W3,
                                                  const float* __restrict__ b3,
                                                  float* __restrict__ out) {
    __shared__ float h1s[EB][65];
    const int tid = threadIdx.x;
    const int w = tid >> 6, lane = tid & 63;
    const int base = blockIdx.x * EB + w * 64;

    int ee = base + lane;
    if (ee >= NE) ee = NE - 1;
    int se = src[ee];
    int de = dst[ee];
    float b1v = b1[lane];

    #pragma unroll 8
    for (int i = 0; i < 64; ++i) {
        int s = __shfl(se, i, 64);
        int d = __shfl(de, i, 64);
        float v = A[(size_t)s * 64 + lane] + B[(size_t)d * 64 + lane] + b1v;
        h1s[w * 64 + i][lane] = fmaxf(v, 0.0f);
    }
    __syncthreads();

    int e = blockIdx.x * EB + tid;
    if (e >= NE) return;

    float h2[32];
    #pragma unroll
    for (int j = 0; j < 32; ++j) h2[j] = b2[j];
    #pragma unroll
    for (int k = 0; k < 64; ++k) {
        float hk = h1s[tid][k];
        const float* wr = W2 + (size_t)k * 32;
        #pragma unroll
        for (int j = 0; j < 32; ++j) h2[j] = fmaf(hk, wr[j], h2[j]);
    }

    float o0 = b3[0], o1 = b3[1];
    #pragma unroll
    for (int k = 0; k < 32; ++k) {
        float hk = fmaxf(h2[k], 0.0f);
        o0 = fmaf(hk, W3[2 * k + 0], o0);
        o1 = fmaf(hk, W3[2 * k + 1], o1);
    }
    *reinterpret_cast<float2*>(out + (size_t)2 * e) = make_float2(o0, o1);
}

// ---------------- launch ----------------
extern "C" void kernel_launch(void* const* d_in, const int* in_sizes, int n_in,
                              void* d_out, int out_size, void* d_ws, size_t ws_size,
                              hipStream_t stream) {
    const float* x    = (const float*)d_in[0];
    const int*   ei   = (const int*)d_in[1];
    const int*   src  = ei;
    const int*   dst  = ei + NE;
    const float* W1   = (const float*)d_in[2];
    const float* b1   = (const float*)d_in[3];
    const float* g1   = (const float*)d_in[4];
    const float* be1  = (const float*)d_in[5];
    const float* W2   = (const float*)d_in[6];
    const float* b2   = (const float*)d_in[7];
    const float* g2   = (const float*)d_in[8];
    const float* be2  = (const float*)d_in[9];
    const float* W3   = (const float*)d_in[10];
    const float* b3   = (const float*)d_in[11];
    const float* We1  = (const float*)d_in[12];
    const float* bme1 = (const float*)d_in[13];
    const float* We2  = (const float*)d_in[14];
    const float* bme2 = (const float*)d_in[15];
    const float* We3  = (const float*)d_in[16];
    const float* bme3 = (const float*)d_in[17];
    float* out = (float*)d_out;
    char* ws = (char*)d_ws;

    float* dsq      = (float*)ws;                         ws += NPAD * 4;
    float* stats    = (float*)ws;                         ws += 1024 * 4;
    int*   cnt      = (int*)ws;                           ws += NPAD * 4;
    int*   cursor   = (int*)ws;                           ws += NPAD * 4;
    int*   bsum     = (int*)ws;                           ws += 256 * 4;
    int*   row_start= (int*)ws;                           ws += (NPAD + 16) * 4;
    unsigned short* pk2 = (unsigned short*)ws;            ws += (size_t)NE * 2;
    ws += 64;  // alignment pad
    unsigned short* bufHb = (unsigned short*)ws;          ws += (size_t)NN * 256 * 2;
    float* bufO     = (float*)ws;                         ws += (size_t)NN * 256 * 4;

    const int nblkE = (NE + 255) / 256;
    const int nblkNode = (NN + 3) / 4;

    // ---- CSR build + degree terms ----
    hipMemsetAsync(cnt, 0, NPAD * sizeof(int), stream);
    k_count_int<<<nblkE, 256, 0, stream>>>(dst, cnt);
    k_bsum<<<SCAN_BLOCKS, 256, 0, stream>>>(cnt, bsum);
    k_scan_bsum<<<1, 256, 0, stream>>>(bsum);
    k_scan_fin<<<SCAN_BLOCKS, 256, 0, stream>>>(cnt, bsum, row_start, cursor, dsq);
    k_fill<<<nblkE, 256, 0, stream>>>(src, dst, cursor, pk2);

    // ---- layer 1: 256 -> 256 (bf16+dsq-scaled gemm), agg, BN stats ----
    {
        dim3 g(2, (NN + 127) / 128);
        k_gemm128_bf<<<g, 256, 0, stream>>>(x, W1, bufHb, NN, 256, 256, dsq);
    }
    k_agg256_b<<<nblkNode, 256, 0, stream>>>(bufHb, row_start, pk2, dsq, b1, bufO);
    hipMemsetAsync(stats, 0, 1024 * sizeof(float), stream);
    k_bn_stats<256><<<256, 256, 0, stream>>>(bufO, stats);
    k_bn_fin<<<1, 256, 0, stream>>>(stats, 256);

    // ---- layer 2: A = BN1(bufO) fused; 256 -> 64 (bf16+scale); agg; BN2 stats ----
    {
        dim3 g(1, (NN + 63) / 64);
        k_gemm<true, true><<<g, 256, 0, stream>>>(bufO, W2, nullptr, bufHb, NN, 256, 64, stats, g1, be1, dsq);
    }
    k_agg64_b<false><<<nblkNode, 256, 0, stream>>>(bufHb, row_start, pk2, dsq, b2, bufO);
    hipMemsetAsync(stats, 0, 1024 * sizeof(float), stream);
    k_bn_stats<64><<<256, 256, 0, stream>>>(bufO, stats);
    k_bn_fin<<<1, 256, 0, stream>>>(stats, 64);

    // ---- layer 3: A = BN2(bufO) fused; 64 -> 64 (bf16+scale); agg + relu ----
    {
        dim3 g(1, (NN + 63) / 64);
        k_gemm<true, true><<<g, 256, 0, stream>>>(bufO, W3, nullptr, bufHb, NN, 64, 64, stats, g2, be2, dsq);
    }
    k_agg64_b<true><<<nblkNode, 256, 0, stream>>>(bufHb, row_start, pk2, dsq, b3, bufO);

    // ---- layer 4: 64 -> 64 (bf16+scale, same W3/b3, no relu) -> emb in bufO ----
    {
        dim3 g(1, (NN + 63) / 64);
        k_gemm<false, true><<<g, 256, 0, stream>>>(bufO, W3, nullptr, bufHb, NN, 64, 64, nullptr, nullptr, nullptr, dsq);
    }
    k_agg64_b<false><<<nblkNode, 256, 0, stream>>>(bufHb, row_start, pk2, dsq, b3, bufO);

    // ---- edge MLP, factored layer 1 (fp32 gemms; reuse bufHb region for A/B) ----
    float* Abuf = (float*)bufHb;
    float* Bbuf = Abuf + (size_t)NN * 64;
    {
        dim3 g(1, (NN + 63) / 64);
        k_gemm<false, false><<<g, 256, 0, stream>>>(bufO, We1, Abuf, nullptr, NN, 64, 64, nullptr, nullptr, nullptr, nullptr);
        k_gemm<false, false><<<g, 256, 0, stream>>>(bufO, We1 + (size_t)64 * 64, Bbuf, nullptr, NN, 64, 64, nullptr, nullptr, nullptr, nullptr);
    }
    k_edge_mlp3<<<(NE + EB - 1) / EB, EB, 0, stream>>>(Abuf, Bbuf, src, dst, bme1, We2, bme2, We3, bme3, out);

    (void)in_sizes; (void)n_in; (void)out_size; (void)ws_size;
}

// Round 12
// 654.868 us; speedup vs baseline: 1.7803x; 1.0393x over previous
//
#include <hip/hip_runtime.h>
#include <hip/hip_bf16.h>
#include <cstddef>

#define NN 50000
#define NE 800000
#define NPAD 50176
#define SCAN_BLOCKS 196   // ceil(NN/256)
#define BN_EPS 1e-5f
#define EB 256            // edges per block in edge MLP (4 waves)

__device__ __forceinline__ unsigned short f2bf(float f) {
    __hip_bfloat16 h = __float2bfloat16(f);
    return *reinterpret_cast<unsigned short*>(&h);
}
__device__ __forceinline__ float bf2f(unsigned short u) {
    return __uint_as_float(((unsigned int)u) << 16);
}

// ---------------- CSR build ----------------
__global__ __launch_bounds__(256) void k_count_int(const int* __restrict__ dst,
                                                   int* __restrict__ cnt) {
    int e = blockIdx.x * 256 + threadIdx.x;
    if (e < NE) atomicAdd(&cnt[dst[e]], 1);
}

__global__ __launch_bounds__(256) void k_bsum(const int* __restrict__ cnt,
                                              int* __restrict__ bsum) {
    __shared__ int red[4];
    int i = blockIdx.x * 256 + threadIdx.x;
    int v = (i < NN) ? cnt[i] : 0;
    #pragma unroll
    for (int off = 32; off > 0; off >>= 1) v += __shfl_down(v, off, 64);
    int lane = threadIdx.x & 63, w = threadIdx.x >> 6;
    if (lane == 0) red[w] = v;
    __syncthreads();
    if (threadIdx.x == 0) bsum[blockIdx.x] = red[0] + red[1] + red[2] + red[3];
}

__global__ __launch_bounds__(256) void k_scan_bsum(int* __restrict__ bsum) {
    __shared__ int tmp[256];
    int t = threadIdx.x;
    int v = (t < SCAN_BLOCKS) ? bsum[t] : 0;
    tmp[t] = v;
    __syncthreads();
    #pragma unroll
    for (int off = 1; off < 256; off <<= 1) {
        int u = (t >= off) ? tmp[t - off] : 0;
        __syncthreads();
        tmp[t] += u;
        __syncthreads();
    }
    if (t < SCAN_BLOCKS) bsum[t] = tmp[t] - v;  // exclusive
}

__global__ __launch_bounds__(256) void k_scan_fin(const int* __restrict__ cnt,
                                                  const int* __restrict__ bsum,
                                                  int* __restrict__ row_start,
                                                  int* __restrict__ cursor,
                                                  float* __restrict__ dsq) {
    __shared__ int tmp[256];
    int t = threadIdx.x;
    int i = blockIdx.x * 256 + t;
    int c = (i < NN) ? cnt[i] : 0;
    tmp[t] = c;
    __syncthreads();
    #pragma unroll
    for (int off = 1; off < 256; off <<= 1) {
        int u = (t >= off) ? tmp[t - off] : 0;
        __syncthreads();
        tmp[t] += u;
        __syncthreads();
    }
    int excl = tmp[t] - c + bsum[blockIdx.x];
    if (i < NN) {
        row_start[i] = excl;
        cursor[i] = excl;
        dsq[i] = rsqrtf((float)c + 1.0f);
    }
    if (i == 0) row_start[NN] = NE;
}

// fill compact CSR entries: src as ushort (NN < 65536)
__global__ __launch_bounds__(256) void k_fill(const int* __restrict__ src,
                                              const int* __restrict__ dst,
                                              int* __restrict__ cursor,
                                              unsigned short* __restrict__ pk2) {
    int e = blockIdx.x * 256 + threadIdx.x;
    if (e < NE) {
        int pos = atomicAdd(&cursor[dst[e]], 1);
        pk2[pos] = (unsigned short)src[e];
    }
}

// ---------------- fp32 tiled GEMM, 64x64 tile ----------------
// BN: fused batchnorm+relu on A-read. OBF: bf16 output (scaled by dsq[row] if dsq != null).
template <bool BN, bool OBF>
__global__ __launch_bounds__(256) void k_gemm(const float* __restrict__ A,
                                              const float* __restrict__ B,
                                              float* __restrict__ Cf,
                                              unsigned short* __restrict__ Cb,
                                              int M, int K, int N,
                                              const float* __restrict__ stats,
                                              const float* __restrict__ g,
                                              const float* __restrict__ be,
                                              const float* __restrict__ dsq) {
    __shared__ float As[16][68];
    __shared__ float Bs[16][68];
    const int tid = threadIdx.x;
    const int tx = tid & 15, ty = tid >> 4;
    const int row0 = blockIdx.y * 64, col0 = blockIdx.x * 64;
    float acc[4][4] = {};

    for (int kk = 0; kk < K; kk += 16) {
        #pragma unroll
        for (int i = 0; i < 4; ++i) {
            int idx = tid + i * 256;
            int m = idx >> 4, k = idx & 15;
            int gr = row0 + m;
            float v = (gr < M) ? A[(size_t)gr * K + kk + k] : 0.0f;
            if (BN) {
                int c = kk + k;
                v = fmaxf((v - stats[c]) * stats[K + c] * g[c] + be[c], 0.0f);
            }
            As[k][m] = v;
        }
        #pragma unroll
        for (int i = 0; i < 4; ++i) {
            int idx = tid + i * 256;
            int k = idx >> 6, n = idx & 63;
            Bs[k][n] = B[(size_t)(kk + k) * N + col0 + n];
        }
        __syncthreads();
        #pragma unroll
        for (int k = 0; k < 16; ++k) {
            float4 a4 = *reinterpret_cast<const float4*>(&As[k][ty * 4]);
            float4 b4 = *reinterpret_cast<const float4*>(&Bs[k][tx * 4]);
            float av[4] = {a4.x, a4.y, a4.z, a4.w};
            float bv[4] = {b4.x, b4.y, b4.z, b4.w};
            #pragma unroll
            for (int i = 0; i < 4; ++i)
                #pragma unroll
                for (int j = 0; j < 4; ++j)
                    acc[i][j] = fmaf(av[i], bv[j], acc[i][j]);
        }
        __syncthreads();
    }
    #pragma unroll
    for (int i = 0; i < 4; ++i) {
        int gr = row0 + ty * 4 + i;
        if (gr < M) {
            if (OBF) {
                float sc = dsq ? dsq[gr] : 1.0f;
                ushort4 u;
                u.x = f2bf(acc[i][0] * sc);
                u.y = f2bf(acc[i][1] * sc);
                u.z = f2bf(acc[i][2] * sc);
                u.w = f2bf(acc[i][3] * sc);
                *reinterpret_cast<ushort4*>(&Cb[(size_t)gr * N + col0 + tx * 4]) = u;
            } else {
                float4 v = make_float4(acc[i][0], acc[i][1], acc[i][2], acc[i][3]);
                *reinterpret_cast<float4*>(&Cf[(size_t)gr * N + col0 + tx * 4]) = v;
            }
        }
    }
}

// ---------------- fp32 GEMM, 128x128 tile, 8x8 micro, BK=8; bf16 dsq-scaled output ----
__global__ __launch_bounds__(256) void k_gemm128_bf(const float* __restrict__ A,
                                                    const float* __restrict__ B,
                                                    unsigned short* __restrict__ Cb,
                                                    int M, int K, int N,
                                                    const float* __restrict__ dsq) {
    __shared__ float As[8][132];
    __shared__ float Bs[8][132];
    const int tid = threadIdx.x;
    const int tx = tid & 15, ty = tid >> 4;
    const int row0 = blockIdx.y * 128, col0 = blockIdx.x * 128;
    float acc[8][8] = {};

    for (int kk = 0; kk < K; kk += 8) {
        {
            int m = tid >> 1;
            int k4 = (tid & 1) * 4;
            int gr = row0 + m;
            float4 v = make_float4(0.f, 0.f, 0.f, 0.f);
            if (gr < M) v = *reinterpret_cast<const float4*>(&A[(size_t)gr * K + kk + k4]);
            As[k4 + 0][m] = v.x;
            As[k4 + 1][m] = v.y;
            As[k4 + 2][m] = v.z;
            As[k4 + 3][m] = v.w;
        }
        {
            int k = tid >> 5;
            int n = (tid & 31) * 4;
            *reinterpret_cast<float4*>(&Bs[k][n]) =
                *reinterpret_cast<const float4*>(&B[(size_t)(kk + k) * N + col0 + n]);
        }
        __syncthreads();
        #pragma unroll
        for (int k = 0; k < 8; ++k) {
            float a[8], b[8];
            *reinterpret_cast<float4*>(&a[0]) = *reinterpret_cast<const float4*>(&As[k][ty * 4]);
            *reinterpret_cast<float4*>(&a[4]) = *reinterpret_cast<const float4*>(&As[k][64 + ty * 4]);
            *reinterpret_cast<float4*>(&b[0]) = *reinterpret_cast<const float4*>(&Bs[k][tx * 4]);
            *reinterpret_cast<float4*>(&b[4]) = *reinterpret_cast<const float4*>(&Bs[k][64 + tx * 4]);
            #pragma unroll
            for (int i = 0; i < 8; ++i)
                #pragma unroll
                for (int j = 0; j < 8; ++j)
                    acc[i][j] = fmaf(a[i], b[j], acc[i][j]);
        }
        __syncthreads();
    }
    #pragma unroll
    for (int i = 0; i < 8; ++i) {
        int gr = row0 + (i < 4 ? ty * 4 + i : 64 + ty * 4 + (i - 4));
        if (gr < M) {
            float sc = dsq[gr];
            ushort4 u0, u1;
            u0.x = f2bf(acc[i][0] * sc); u0.y = f2bf(acc[i][1] * sc);
            u0.z = f2bf(acc[i][2] * sc); u0.w = f2bf(acc[i][3] * sc);
            u1.x = f2bf(acc[i][4] * sc); u1.y = f2bf(acc[i][5] * sc);
            u1.z = f2bf(acc[i][6] * sc); u1.w = f2bf(acc[i][7] * sc);
            *reinterpret_cast<ushort4*>(&Cb[(size_t)gr * N + col0 + tx * 4]) = u0;
            *reinterpret_cast<ushort4*>(&Cb[(size_t)gr * N + col0 + 64 + tx * 4]) = u1;
        }
    }
}

// ---------------- CSR aggregation, D=256, bf16 rows (pre-scaled by dsq), pure sum ----
__global__ __launch_bounds__(256) void k_agg256_b(const unsigned short* __restrict__ hb,
                                                  const int* __restrict__ row_start,
                                                  const unsigned short* __restrict__ pk2,
                                                  const float* __restrict__ dsq,
                                                  const float* __restrict__ b,
                                                  float* __restrict__ out) {
    int d = blockIdx.x * 4 + (threadIdx.x >> 6);
    if (d >= NN) return;
    int lane = threadIdx.x & 63;
    int rs = row_start[d], re = row_start[d + 1];
    float4 acc0 = make_float4(0.f, 0.f, 0.f, 0.f);
    float4 acc1 = make_float4(0.f, 0.f, 0.f, 0.f);
    int j = rs;
    for (; j + 2 <= re; j += 2) {
        int s0 = (int)pk2[j];
        int s1 = (int)pk2[j + 1];
        ushort4 v0 = *reinterpret_cast<const ushort4*>(hb + (size_t)s0 * 256 + lane * 4);
        ushort4 v1 = *reinterpret_cast<const ushort4*>(hb + (size_t)s1 * 256 + lane * 4);
        acc0.x += bf2f(v0.x); acc0.y += bf2f(v0.y); acc0.z += bf2f(v0.z); acc0.w += bf2f(v0.w);
        acc1.x += bf2f(v1.x); acc1.y += bf2f(v1.y); acc1.z += bf2f(v1.z); acc1.w += bf2f(v1.w);
    }
    if (j < re) {
        int s0 = (int)pk2[j];
        ushort4 v0 = *reinterpret_cast<const ushort4*>(hb + (size_t)s0 * 256 + lane * 4);
        acc0.x += bf2f(v0.x); acc0.y += bf2f(v0.y); acc0.z += bf2f(v0.z); acc0.w += bf2f(v0.w);
    }
    float sd = dsq[d];
    ushort4 hv = *reinterpret_cast<const ushort4*>(hb + (size_t)d * 256 + lane * 4);
    float4 bv = *reinterpret_cast<const float4*>(b + lane * 4);
    float4 o;
    o.x = fmaf(sd, acc0.x + acc1.x + bf2f(hv.x), bv.x);
    o.y = fmaf(sd, acc0.y + acc1.y + bf2f(hv.y), bv.y);
    o.z = fmaf(sd, acc0.z + acc1.z + bf2f(hv.z), bv.z);
    o.w = fmaf(sd, acc0.w + acc1.w + bf2f(hv.w), bv.w);
    *reinterpret_cast<float4*>(out + (size_t)d * 256 + lane * 4) = o;
}

// ---------------- CSR aggregation, D=64, bf16 rows (pre-scaled), pure sum ----------------
template <bool RELU>
__global__ __launch_bounds__(256) void k_agg64_b(const unsigned short* __restrict__ hb,
                                                 const int* __restrict__ row_start,
                                                 const unsigned short* __restrict__ pk2,
                                                 const float* __restrict__ dsq,
                                                 const float* __restrict__ b,
                                                 float* __restrict__ out) {
    int d = blockIdx.x * 4 + (threadIdx.x >> 6);
    if (d >= NN) return;
    int lane = threadIdx.x & 63;
    int rs = row_start[d], re = row_start[d + 1];
    float acc0 = 0.0f, acc1 = 0.0f;
    int j = rs;
    for (; j + 2 <= re; j += 2) {
        int s0 = (int)pk2[j];
        int s1 = (int)pk2[j + 1];
        acc0 += bf2f(hb[(size_t)s0 * 64 + lane]);
        acc1 += bf2f(hb[(size_t)s1 * 64 + lane]);
    }
    if (j < re) {
        int s0 = (int)pk2[j];
        acc0 += bf2f(hb[(size_t)s0 * 64 + lane]);
    }
    float o = fmaf(dsq[d], acc0 + acc1 + bf2f(hb[(size_t)d * 64 + lane]), b[lane]);
    if (RELU) o = fmaxf(o, 0.0f);
    out[(size_t)d * 64 + lane] = o;
}

// ---------------- BatchNorm stats ----------------
template <int C>
__global__ __launch_bounds__(256) void k_bn_stats(const float* __restrict__ x,
                                                  float* __restrict__ stats) {
    int c = threadIdx.x & (C - 1);
    int rstart = blockIdx.x * (256 / C) + (threadIdx.x / C);
    int rstride = gridDim.x * (256 / C);
    float s = 0.0f, ss = 0.0f;
    for (int r = rstart; r < NN; r += rstride) {
        float v = x[(size_t)r * C + c];
        s += v;
        ss += v * v;
    }
    atomicAdd(&stats[c], s);
    atomicAdd(&stats[C + c], ss);
}

__global__ __launch_bounds__(256) void k_bn_fin(float* __restrict__ stats, int C) {
    int c = threadIdx.x;
    if (c < C) {
        const float invN = 1.0f / (float)NN;
        float mean = stats[c] * invN;
        float var = stats[C + c] * invN - mean * mean;
        stats[c] = mean;
        stats[C + c] = rsqrtf(var + BN_EPS);
    }
}

// ---------------- edge MLP v4: bf16 A/B, bf16 LDS, pair-gather, EB=256 ----------------
__global__ __launch_bounds__(EB) void k_edge_mlp4(const unsigned short* __restrict__ A,
                                                  const unsigned short* __restrict__ B,
                                                  const int* __restrict__ src,
                                                  const int* __restrict__ dst,
                                                  const float* __restrict__ b1,
                                                  const float* __restrict__ W2,
                                                  const float* __restrict__ b2,
                                                  const float* __restrict__ W3,
                                                  const float* __restrict__ b3,
                                                  float* __restrict__ out) {
    __shared__ unsigned short h1s[EB][66];
    const int tid = threadIdx.x;
    const int w = tid >> 6, lane = tid & 63;
    const int base = blockIdx.x * EB + w * 64;

    int ee = base + lane;
    if (ee >= NE) ee = NE - 1;
    int se = src[ee];
    int de = dst[ee];

    const int eh = lane >> 5;          // which edge of the pair
    const int ch2 = (lane & 31) * 2;   // channel pair
    const float b1v0 = b1[ch2], b1v1 = b1[ch2 + 1];

    // phase 1: 2 edges per iteration; half-wave per edge; lane owns 2 channels
    #pragma unroll 4
    for (int i = 0; i < 32; ++i) {
        int ei = 2 * i + eh;
        int s = __shfl(se, ei, 64);
        int d = __shfl(de, ei, 64);
        ushort2 ua = *reinterpret_cast<const ushort2*>(A + (size_t)s * 64 + ch2);
        ushort2 ub = *reinterpret_cast<const ushort2*>(B + (size_t)d * 64 + ch2);
        float v0 = fmaxf(bf2f(ua.x) + bf2f(ub.x) + b1v0, 0.0f);
        float v1 = fmaxf(bf2f(ua.y) + bf2f(ub.y) + b1v1, 0.0f);
        ushort2 uo;
        uo.x = f2bf(v0);
        uo.y = f2bf(v1);
        *reinterpret_cast<ushort2*>(&h1s[w * 64 + ei][ch2]) = uo;
    }
    __syncthreads();

    // phase 2: one edge per thread, 64->32->2 from LDS
    int e = blockIdx.x * EB + tid;
    if (e >= NE) return;

    float h2[32];
    #pragma unroll
    for (int j = 0; j < 32; ++j) h2[j] = b2[j];
    #pragma unroll
    for (int k2 = 0; k2 < 32; ++k2) {
        ushort2 hp = *reinterpret_cast<const ushort2*>(&h1s[tid][k2 * 2]);
        float hk0 = bf2f(hp.x);
        float hk1 = bf2f(hp.y);
        const float* wr0 = W2 + (size_t)(k2 * 2) * 32;
        const float* wr1 = wr0 + 32;
        #pragma unroll
        for (int j = 0; j < 32; ++j) h2[j] = fmaf(hk0, wr0[j], h2[j]);
        #pragma unroll
        for (int j = 0; j < 32; ++j) h2[j] = fmaf(hk1, wr1[j], h2[j]);
    }

    float o0 = b3[0], o1 = b3[1];
    #pragma unroll
    for (int k = 0; k < 32; ++k) {
        float hk = fmaxf(h2[k], 0.0f);
        o0 = fmaf(hk, W3[2 * k + 0], o0);
        o1 = fmaf(hk, W3[2 * k + 1], o1);
    }
    *reinterpret_cast<float2*>(out + (size_t)2 * e) = make_float2(o0, o1);
}

// ---------------- launch ----------------
extern "C" void kernel_launch(void* const* d_in, const int* in_sizes, int n_in,
                              void* d_out, int out_size, void* d_ws, size_t ws_size,
                              hipStream_t stream) {
    const float* x    = (const float*)d_in[0];
    const int*   ei   = (const int*)d_in[1];
    const int*   src  = ei;
    const int*   dst  = ei + NE;
    const float* W1   = (const float*)d_in[2];
    const float* b1   = (const float*)d_in[3];
    const float* g1   = (const float*)d_in[4];
    const float* be1  = (const float*)d_in[5];
    const float* W2   = (const float*)d_in[6];
    const float* b2   = (const float*)d_in[7];
    const float* g2   = (const float*)d_in[8];
    const float* be2  = (const float*)d_in[9];
    const float* W3   = (const float*)d_in[10];
    const float* b3   = (const float*)d_in[11];
    const float* We1  = (const float*)d_in[12];
    const float* bme1 = (const float*)d_in[13];
    const float* We2  = (const float*)d_in[14];
    const float* bme2 = (const float*)d_in[15];
    const float* We3  = (const float*)d_in[16];
    const float* bme3 = (const float*)d_in[17];
    float* out = (float*)d_out;
    char* ws = (char*)d_ws;

    float* dsq      = (float*)ws;                         ws += NPAD * 4;
    float* stats    = (float*)ws;                         ws += 1024 * 4;
    int*   cnt      = (int*)ws;                           ws += NPAD * 4;
    int*   cursor   = (int*)ws;                           ws += NPAD * 4;
    int*   bsum     = (int*)ws;                           ws += 256 * 4;
    int*   row_start= (int*)ws;                           ws += (NPAD + 16) * 4;
    unsigned short* pk2 = (unsigned short*)ws;            ws += (size_t)NE * 2;
    ws += 64;  // alignment pad
    unsigned short* bufHb = (unsigned short*)ws;          ws += (size_t)NN * 256 * 2;
    float* bufO     = (float*)ws;                         ws += (size_t)NN * 256 * 4;

    const int nblkE = (NE + 255) / 256;
    const int nblkNode = (NN + 3) / 4;

    // ---- CSR build + degree terms ----
    hipMemsetAsync(cnt, 0, NPAD * sizeof(int), stream);
    k_count_int<<<nblkE, 256, 0, stream>>>(dst, cnt);
    k_bsum<<<SCAN_BLOCKS, 256, 0, stream>>>(cnt, bsum);
    k_scan_bsum<<<1, 256, 0, stream>>>(bsum);
    k_scan_fin<<<SCAN_BLOCKS, 256, 0, stream>>>(cnt, bsum, row_start, cursor, dsq);
    k_fill<<<nblkE, 256, 0, stream>>>(src, dst, cursor, pk2);

    // ---- layer 1: 256 -> 256 (bf16+dsq-scaled gemm), agg, BN stats ----
    {
        dim3 g(2, (NN + 127) / 128);
        k_gemm128_bf<<<g, 256, 0, stream>>>(x, W1, bufHb, NN, 256, 256, dsq);
    }
    k_agg256_b<<<nblkNode, 256, 0, stream>>>(bufHb, row_start, pk2, dsq, b1, bufO);
    hipMemsetAsync(stats, 0, 1024 * sizeof(float), stream);
    k_bn_stats<256><<<256, 256, 0, stream>>>(bufO, stats);
    k_bn_fin<<<1, 256, 0, stream>>>(stats, 256);

    // ---- layer 2: A = BN1(bufO) fused; 256 -> 64 (bf16+scale); agg; BN2 stats ----
    {
        dim3 g(1, (NN + 63) / 64);
        k_gemm<true, true><<<g, 256, 0, stream>>>(bufO, W2, nullptr, bufHb, NN, 256, 64, stats, g1, be1, dsq);
    }
    k_agg64_b<false><<<nblkNode, 256, 0, stream>>>(bufHb, row_start, pk2, dsq, b2, bufO);
    hipMemsetAsync(stats, 0, 1024 * sizeof(float), stream);
    k_bn_stats<64><<<256, 256, 0, stream>>>(bufO, stats);
    k_bn_fin<<<1, 256, 0, stream>>>(stats, 64);

    // ---- layer 3: A = BN2(bufO) fused; 64 -> 64 (bf16+scale); agg + relu ----
    {
        dim3 g(1, (NN + 63) / 64);
        k_gemm<true, true><<<g, 256, 0, stream>>>(bufO, W3, nullptr, bufHb, NN, 64, 64, stats, g2, be2, dsq);
    }
    k_agg64_b<true><<<nblkNode, 256, 0, stream>>>(bufHb, row_start, pk2, dsq, b3, bufO);

    // ---- layer 4: 64 -> 64 (bf16+scale, same W3/b3, no relu) -> emb in bufO ----
    {
        dim3 g(1, (NN + 63) / 64);
        k_gemm<false, true><<<g, 256, 0, stream>>>(bufO, W3, nullptr, bufHb, NN, 64, 64, nullptr, nullptr, nullptr, dsq);
    }
    k_agg64_b<false><<<nblkNode, 256, 0, stream>>>(bufHb, row_start, pk2, dsq, b3, bufO);

    // ---- edge MLP, factored layer 1 -> bf16 A/B buffers ----
    unsigned short* Abuf = bufHb;                     // NN*64 ushort
    unsigned short* Bbuf = bufHb + (size_t)NN * 64;   // NN*64 ushort
    {
        dim3 g(1, (NN + 63) / 64);
        k_gemm<false, true><<<g, 256, 0, stream>>>(bufO, We1, nullptr, Abuf, NN, 64, 64, nullptr, nullptr, nullptr, nullptr);
        k_gemm<false, true><<<g, 256, 0, stream>>>(bufO, We1 + (size_t)64 * 64, nullptr, Bbuf, NN, 64, 64, nullptr, nullptr, nullptr, nullptr);
    }
    k_edge_mlp4<<<(NE + EB - 1) / EB, EB, 0, stream>>>(Abuf, Bbuf, src, dst, bme1, We2, bme2, We3, bme3, out);

    (void)in_sizes; (void)n_in; (void)out_size; (void)ws_size;
}

// Round 13
// 562.741 us; speedup vs baseline: 2.0718x; 1.1637x over previous
//
#include <hip/hip_runtime.h>
#include <hip/hip_bf16.h>
#include <cstddef>

#define NN 50000
#define NE 800000
#define NPAD 50176
#define SCAN_BLOCKS 196   // ceil(NN/256)
#define BN_EPS 1e-5f
#define EB 256            // edges per block in edge MLP (4 waves)

typedef __bf16 bf16x8f __attribute__((ext_vector_type(8)));
typedef unsigned short u16x8 __attribute__((ext_vector_type(8)));
typedef float f32x4 __attribute__((ext_vector_type(4)));

__device__ __forceinline__ unsigned short f2bf(float f) {
    __hip_bfloat16 h = __float2bfloat16(f);
    return *reinterpret_cast<unsigned short*>(&h);
}
__device__ __forceinline__ float bf2f(unsigned short u) {
    return __uint_as_float(((unsigned int)u) << 16);
}

// ---------------- CSR build ----------------
__global__ __launch_bounds__(256) void k_count_int(const int* __restrict__ dst,
                                                   int* __restrict__ cnt) {
    int e = blockIdx.x * 256 + threadIdx.x;
    if (e < NE) atomicAdd(&cnt[dst[e]], 1);
}

__global__ __launch_bounds__(256) void k_bsum(const int* __restrict__ cnt,
                                              int* __restrict__ bsum) {
    __shared__ int red[4];
    int i = blockIdx.x * 256 + threadIdx.x;
    int v = (i < NN) ? cnt[i] : 0;
    #pragma unroll
    for (int off = 32; off > 0; off >>= 1) v += __shfl_down(v, off, 64);
    int lane = threadIdx.x & 63, w = threadIdx.x >> 6;
    if (lane == 0) red[w] = v;
    __syncthreads();
    if (threadIdx.x == 0) bsum[blockIdx.x] = red[0] + red[1] + red[2] + red[3];
}

__global__ __launch_bounds__(256) void k_scan_bsum(int* __restrict__ bsum) {
    __shared__ int tmp[256];
    int t = threadIdx.x;
    int v = (t < SCAN_BLOCKS) ? bsum[t] : 0;
    tmp[t] = v;
    __syncthreads();
    #pragma unroll
    for (int off = 1; off < 256; off <<= 1) {
        int u = (t >= off) ? tmp[t - off] : 0;
        __syncthreads();
        tmp[t] += u;
        __syncthreads();
    }
    if (t < SCAN_BLOCKS) bsum[t] = tmp[t] - v;  // exclusive
}

__global__ __launch_bounds__(256) void k_scan_fin(const int* __restrict__ cnt,
                                                  const int* __restrict__ bsum,
                                                  int* __restrict__ row_start,
                                                  int* __restrict__ cursor,
                                                  float* __restrict__ dsq) {
    __shared__ int tmp[256];
    int t = threadIdx.x;
    int i = blockIdx.x * 256 + t;
    int c = (i < NN) ? cnt[i] : 0;
    tmp[t] = c;
    __syncthreads();
    #pragma unroll
    for (int off = 1; off < 256; off <<= 1) {
        int u = (t >= off) ? tmp[t - off] : 0;
        __syncthreads();
        tmp[t] += u;
        __syncthreads();
    }
    int excl = tmp[t] - c + bsum[blockIdx.x];
    if (i < NN) {
        row_start[i] = excl;
        cursor[i] = excl;
        dsq[i] = rsqrtf((float)c + 1.0f);
    }
    if (i == 0) row_start[NN] = NE;
}

// fill compact CSR entries: src as ushort (NN < 65536)
__global__ __launch_bounds__(256) void k_fill(const int* __restrict__ src,
                                              const int* __restrict__ dst,
                                              int* __restrict__ cursor,
                                              unsigned short* __restrict__ pk2) {
    int e = blockIdx.x * 256 + threadIdx.x;
    if (e < NE) {
        int pos = atomicAdd(&cursor[dst[e]], 1);
        pk2[pos] = (unsigned short)src[e];
    }
}

// ---------------- MFMA bf16 GEMM: C(bf16) = A(f32) @ B(f32) ----------------
// BM=128, BK=32, BNT in {64,128}. 4 waves; wave owns 32 rows (2 row-tiles of 16).
// BNA: fused batchnorm+relu on A-read. SCALE: output scaled by dsq[row].
// LDS: As[row][k] u16 stride 56; Bs[col][k] u16 stride 56 (B transposed in LDS).
template <int BNT, bool BNA, bool SCALE>
__global__ __launch_bounds__(256) void k_gemm_mfma(const float* __restrict__ A,
                                                   const float* __restrict__ B,
                                                   unsigned short* __restrict__ Cb,
                                                   int M, int K, int N,
                                                   const float* __restrict__ stats,
                                                   const float* __restrict__ g,
                                                   const float* __restrict__ be,
                                                   const float* __restrict__ dsq) {
    __shared__ unsigned short As[128 * 56];
    __shared__ unsigned short Bs[BNT * 56];
    const int tid = threadIdx.x;
    const int lane = tid & 63, wave = tid >> 6;
    const int row0 = blockIdx.y * 128, col0 = blockIdx.x * BNT;
    constexpr int NCT = BNT / 16;

    f32x4 acc[2][NCT] = {};

    const int r16 = lane & 15;
    const int kg = (lane >> 4) * 8;

    for (int k0 = 0; k0 < K; k0 += 32) {
        // ---- stage A: 128 rows x 32 k (f32 -> bf16, optional BN+relu) ----
        {
            int row = tid >> 1;
            int kh = (tid & 1) * 16;
            int gr = row0 + row;
            unsigned short tmp[16];
            if (gr < M) {
                const float* ap = A + (size_t)gr * K + k0 + kh;
                #pragma unroll
                for (int j = 0; j < 16; ++j) {
                    float v = ap[j];
                    if constexpr (BNA) {
                        int c = k0 + kh + j;
                        v = fmaxf((v - stats[c]) * stats[K + c] * g[c] + be[c], 0.0f);
                    }
                    tmp[j] = f2bf(v);
                }
            } else {
                #pragma unroll
                for (int j = 0; j < 16; ++j) tmp[j] = 0;
            }
            unsigned short* dp = &As[row * 56 + kh];
            *reinterpret_cast<u16x8*>(dp) = *reinterpret_cast<const u16x8*>(&tmp[0]);
            *reinterpret_cast<u16x8*>(dp + 8) = *reinterpret_cast<const u16x8*>(&tmp[8]);
        }
        // ---- stage B transposed: Bs[col][k] ----
        {
            constexpr int JC = (BNT == 128) ? 16 : 8;
            int col = tid & (BNT - 1);
            int kh = (tid / BNT) * JC;
            unsigned short tmp[JC];
            #pragma unroll
            for (int j = 0; j < JC; ++j)
                tmp[j] = f2bf(B[(size_t)(k0 + kh + j) * N + col0 + col]);
            unsigned short* dp = &Bs[col * 56 + kh];
            #pragma unroll
            for (int j = 0; j < JC; j += 8)
                *reinterpret_cast<u16x8*>(dp + j) = *reinterpret_cast<const u16x8*>(&tmp[j]);
        }
        __syncthreads();

        // ---- MFMA ----
        bf16x8f af[2];
        bf16x8f bfr[NCT];
        #pragma unroll
        for (int rt = 0; rt < 2; ++rt)
            af[rt] = __builtin_bit_cast(bf16x8f,
                *reinterpret_cast<const u16x8*>(&As[(wave * 32 + rt * 16 + r16) * 56 + kg]));
        #pragma unroll
        for (int ct = 0; ct < NCT; ++ct)
            bfr[ct] = __builtin_bit_cast(bf16x8f,
                *reinterpret_cast<const u16x8*>(&Bs[(ct * 16 + r16) * 56 + kg]));
        #pragma unroll
        for (int rt = 0; rt < 2; ++rt)
            #pragma unroll
            for (int ct = 0; ct < NCT; ++ct)
                acc[rt][ct] = __builtin_amdgcn_mfma_f32_16x16x32_bf16(af[rt], bfr[ct], acc[rt][ct], 0, 0, 0);
        __syncthreads();
    }

    // ---- epilogue: C/D layout col=lane&15, row=(lane>>4)*4+reg ----
    const int rg = (lane >> 4) * 4;
    #pragma unroll
    for (int rt = 0; rt < 2; ++rt) {
        #pragma unroll
        for (int r = 0; r < 4; ++r) {
            int gr = row0 + wave * 32 + rt * 16 + rg + r;
            if (gr < M) {
                float sc = 1.0f;
                if constexpr (SCALE) sc = dsq[gr];
                #pragma unroll
                for (int ct = 0; ct < NCT; ++ct)
                    Cb[(size_t)gr * N + col0 + ct * 16 + r16] = f2bf(acc[rt][ct][r] * sc);
            }
        }
    }
}

// ---------------- CSR aggregation, D=256, bf16 rows (pre-scaled by dsq), pure sum ----
__global__ __launch_bounds__(256) void k_agg256_b(const unsigned short* __restrict__ hb,
                                                  const int* __restrict__ row_start,
                                                  const unsigned short* __restrict__ pk2,
                                                  const float* __restrict__ dsq,
                                                  const float* __restrict__ b,
                                                  float* __restrict__ out) {
    int d = blockIdx.x * 4 + (threadIdx.x >> 6);
    if (d >= NN) return;
    int lane = threadIdx.x & 63;
    int rs = row_start[d], re = row_start[d + 1];
    float4 acc0 = make_float4(0.f, 0.f, 0.f, 0.f);
    float4 acc1 = make_float4(0.f, 0.f, 0.f, 0.f);
    int j = rs;
    for (; j + 2 <= re; j += 2) {
        int s0 = (int)pk2[j];
        int s1 = (int)pk2[j + 1];
        ushort4 v0 = *reinterpret_cast<const ushort4*>(hb + (size_t)s0 * 256 + lane * 4);
        ushort4 v1 = *reinterpret_cast<const ushort4*>(hb + (size_t)s1 * 256 + lane * 4);
        acc0.x += bf2f(v0.x); acc0.y += bf2f(v0.y); acc0.z += bf2f(v0.z); acc0.w += bf2f(v0.w);
        acc1.x += bf2f(v1.x); acc1.y += bf2f(v1.y); acc1.z += bf2f(v1.z); acc1.w += bf2f(v1.w);
    }
    if (j < re) {
        int s0 = (int)pk2[j];
        ushort4 v0 = *reinterpret_cast<const ushort4*>(hb + (size_t)s0 * 256 + lane * 4);
        acc0.x += bf2f(v0.x); acc0.y += bf2f(v0.y); acc0.z += bf2f(v0.z); acc0.w += bf2f(v0.w);
    }
    float sd = dsq[d];
    ushort4 hv = *reinterpret_cast<const ushort4*>(hb + (size_t)d * 256 + lane * 4);
    float4 bv = *reinterpret_cast<const float4*>(b + lane * 4);
    float4 o;
    o.x = fmaf(sd, acc0.x + acc1.x + bf2f(hv.x), bv.x);
    o.y = fmaf(sd, acc0.y + acc1.y + bf2f(hv.y), bv.y);
    o.z = fmaf(sd, acc0.z + acc1.z + bf2f(hv.z), bv.z);
    o.w = fmaf(sd, acc0.w + acc1.w + bf2f(hv.w), bv.w);
    *reinterpret_cast<float4*>(out + (size_t)d * 256 + lane * 4) = o;
}

// ---------------- CSR aggregation, D=64, bf16 rows (pre-scaled), pure sum ----------------
template <bool RELU>
__global__ __launch_bounds__(256) void k_agg64_b(const unsigned short* __restrict__ hb,
                                                 const int* __restrict__ row_start,
                                                 const unsigned short* __restrict__ pk2,
                                                 const float* __restrict__ dsq,
                                                 const float* __restrict__ b,
                                                 float* __restrict__ out) {
    int d = blockIdx.x * 4 + (threadIdx.x >> 6);
    if (d >= NN) return;
    int lane = threadIdx.x & 63;
    int rs = row_start[d], re = row_start[d + 1];
    float acc0 = 0.0f, acc1 = 0.0f;
    int j = rs;
    for (; j + 2 <= re; j += 2) {
        int s0 = (int)pk2[j];
        int s1 = (int)pk2[j + 1];
        acc0 += bf2f(hb[(size_t)s0 * 64 + lane]);
        acc1 += bf2f(hb[(size_t)s1 * 64 + lane]);
    }
    if (j < re) {
        int s0 = (int)pk2[j];
        acc0 += bf2f(hb[(size_t)s0 * 64 + lane]);
    }
    float o = fmaf(dsq[d], acc0 + acc1 + bf2f(hb[(size_t)d * 64 + lane]), b[lane]);
    if (RELU) o = fmaxf(o, 0.0f);
    out[(size_t)d * 64 + lane] = o;
}

// ---------------- BatchNorm stats ----------------
template <int C>
__global__ __launch_bounds__(256) void k_bn_stats(const float* __restrict__ x,
                                                  float* __restrict__ stats) {
    int c = threadIdx.x & (C - 1);
    int rstart = blockIdx.x * (256 / C) + (threadIdx.x / C);
    int rstride = gridDim.x * (256 / C);
    float s = 0.0f, ss = 0.0f;
    for (int r = rstart; r < NN; r += rstride) {
        float v = x[(size_t)r * C + c];
        s += v;
        ss += v * v;
    }
    atomicAdd(&stats[c], s);
    atomicAdd(&stats[C + c], ss);
}

__global__ __launch_bounds__(256) void k_bn_fin(float* __restrict__ stats, int C) {
    int c = threadIdx.x;
    if (c < C) {
        const float invN = 1.0f / (float)NN;
        float mean = stats[c] * invN;
        float var = stats[C + c] * invN - mean * mean;
        stats[c] = mean;
        stats[C + c] = rsqrtf(var + BN_EPS);
    }
}

// ---------------- edge MLP v4: bf16 A/B, bf16 LDS, pair-gather, EB=256 ----------------
__global__ __launch_bounds__(EB) void k_edge_mlp4(const unsigned short* __restrict__ A,
                                                  const unsigned short* __restrict__ B,
                                                  const int* __restrict__ src,
                                                  const int* __restrict__ dst,
                                                  const float* __restrict__ b1,
                                                  const float* __restrict__ W2,
                                                  const float* __restrict__ b2,
                                                  const float* __restrict__ W3,
                                                  const float* __restrict__ b3,
                                                  float* __restrict__ out) {
    __shared__ unsigned short h1s[EB][66];
    const int tid = threadIdx.x;
    const int w = tid >> 6, lane = tid & 63;
    const int base = blockIdx.x * EB + w * 64;

    int ee = base + lane;
    if (ee >= NE) ee = NE - 1;
    int se = src[ee];
    int de = dst[ee];

    const int eh = lane >> 5;          // which edge of the pair
    const int ch2 = (lane & 31) * 2;   // channel pair
    const float b1v0 = b1[ch2], b1v1 = b1[ch2 + 1];

    // phase 1: 2 edges per iteration; half-wave per edge; lane owns 2 channels
    #pragma unroll 4
    for (int i = 0; i < 32; ++i) {
        int ei = 2 * i + eh;
        int s = __shfl(se, ei, 64);
        int d = __shfl(de, ei, 64);
        ushort2 ua = *reinterpret_cast<const ushort2*>(A + (size_t)s * 64 + ch2);
        ushort2 ub = *reinterpret_cast<const ushort2*>(B + (size_t)d * 64 + ch2);
        float v0 = fmaxf(bf2f(ua.x) + bf2f(ub.x) + b1v0, 0.0f);
        float v1 = fmaxf(bf2f(ua.y) + bf2f(ub.y) + b1v1, 0.0f);
        ushort2 uo;
        uo.x = f2bf(v0);
        uo.y = f2bf(v1);
        *reinterpret_cast<ushort2*>(&h1s[w * 64 + ei][ch2]) = uo;
    }
    __syncthreads();

    // phase 2: one edge per thread, 64->32->2 from LDS
    int e = blockIdx.x * EB + tid;
    if (e >= NE) return;

    float h2[32];
    #pragma unroll
    for (int j = 0; j < 32; ++j) h2[j] = b2[j];
    #pragma unroll
    for (int k2 = 0; k2 < 32; ++k2) {
        ushort2 hp = *reinterpret_cast<const ushort2*>(&h1s[tid][k2 * 2]);
        float hk0 = bf2f(hp.x);
        float hk1 = bf2f(hp.y);
        const float* wr0 = W2 + (size_t)(k2 * 2) * 32;
        const float* wr1 = wr0 + 32;
        #pragma unroll
        for (int j = 0; j < 32; ++j) h2[j] = fmaf(hk0, wr0[j], h2[j]);
        #pragma unroll
        for (int j = 0; j < 32; ++j) h2[j] = fmaf(hk1, wr1[j], h2[j]);
    }

    float o0 = b3[0], o1 = b3[1];
    #pragma unroll
    for (int k = 0; k < 32; ++k) {
        float hk = fmaxf(h2[k], 0.0f);
        o0 = fmaf(hk, W3[2 * k + 0], o0);
        o1 = fmaf(hk, W3[2 * k + 1], o1);
    }
    *reinterpret_cast<float2*>(out + (size_t)2 * e) = make_float2(o0, o1);
}

// ---------------- launch ----------------
extern "C" void kernel_launch(void* const* d_in, const int* in_sizes, int n_in,
                              void* d_out, int out_size, void* d_ws, size_t ws_size,
                              hipStream_t stream) {
    const float* x    = (const float*)d_in[0];
    const int*   ei   = (const int*)d_in[1];
    const int*   src  = ei;
    const int*   dst  = ei + NE;
    const float* W1   = (const float*)d_in[2];
    const float* b1   = (const float*)d_in[3];
    const float* g1   = (const float*)d_in[4];
    const float* be1  = (const float*)d_in[5];
    const float* W2   = (const float*)d_in[6];
    const float* b2   = (const float*)d_in[7];
    const float* g2   = (const float*)d_in[8];
    const float* be2  = (const float*)d_in[9];
    const float* W3   = (const float*)d_in[10];
    const float* b3   = (const float*)d_in[11];
    const float* We1  = (const float*)d_in[12];
    const float* bme1 = (const float*)d_in[13];
    const float* We2  = (const float*)d_in[14];
    const float* bme2 = (const float*)d_in[15];
    const float* We3  = (const float*)d_in[16];
    const float* bme3 = (const float*)d_in[17];
    float* out = (float*)d_out;
    char* ws = (char*)d_ws;

    float* dsq      = (float*)ws;                         ws += NPAD * 4;
    float* stats    = (float*)ws;                         ws += 1024 * 4;
    int*   cnt      = (int*)ws;                           ws += NPAD * 4;
    int*   cursor   = (int*)ws;                           ws += NPAD * 4;
    int*   bsum     = (int*)ws;                           ws += 256 * 4;
    int*   row_start= (int*)ws;                           ws += (NPAD + 16) * 4;
    unsigned short* pk2 = (unsigned short*)ws;            ws += (size_t)NE * 2;
    ws += 64;  // alignment pad
    unsigned short* bufHb = (unsigned short*)ws;          ws += (size_t)NN * 256 * 2;
    float* bufO     = (float*)ws;                         ws += (size_t)NN * 256 * 4;

    const int nblkE = (NE + 255) / 256;
    const int nblkNode = (NN + 3) / 4;
    const int gy = (NN + 127) / 128;   // 391

    // ---- CSR build + degree terms ----
    hipMemsetAsync(cnt, 0, NPAD * sizeof(int), stream);
    k_count_int<<<nblkE, 256, 0, stream>>>(dst, cnt);
    k_bsum<<<SCAN_BLOCKS, 256, 0, stream>>>(cnt, bsum);
    k_scan_bsum<<<1, 256, 0, stream>>>(bsum);
    k_scan_fin<<<SCAN_BLOCKS, 256, 0, stream>>>(cnt, bsum, row_start, cursor, dsq);
    k_fill<<<nblkE, 256, 0, stream>>>(src, dst, cursor, pk2);

    // ---- layer 1: 256 -> 256 MFMA (bf16+dsq-scaled out), agg, BN stats ----
    k_gemm_mfma<128, false, true><<<dim3(2, gy), 256, 0, stream>>>(
        x, W1, bufHb, NN, 256, 256, nullptr, nullptr, nullptr, dsq);
    k_agg256_b<<<nblkNode, 256, 0, stream>>>(bufHb, row_start, pk2, dsq, b1, bufO);
    hipMemsetAsync(stats, 0, 1024 * sizeof(float), stream);
    k_bn_stats<256><<<256, 256, 0, stream>>>(bufO, stats);
    k_bn_fin<<<1, 256, 0, stream>>>(stats, 256);

    // ---- layer 2: A = BN1(bufO) fused; 256 -> 64 MFMA; agg; BN2 stats ----
    k_gemm_mfma<64, true, true><<<dim3(1, gy), 256, 0, stream>>>(
        bufO, W2, bufHb, NN, 256, 64, stats, g1, be1, dsq);
    k_agg64_b<false><<<nblkNode, 256, 0, stream>>>(bufHb, row_start, pk2, dsq, b2, bufO);
    hipMemsetAsync(stats, 0, 1024 * sizeof(float), stream);
    k_bn_stats<64><<<256, 256, 0, stream>>>(bufO, stats);
    k_bn_fin<<<1, 256, 0, stream>>>(stats, 64);

    // ---- layer 3: A = BN2(bufO) fused; 64 -> 64 MFMA; agg + relu ----
    k_gemm_mfma<64, true, true><<<dim3(1, gy), 256, 0, stream>>>(
        bufO, W3, bufHb, NN, 64, 64, stats, g2, be2, dsq);
    k_agg64_b<true><<<nblkNode, 256, 0, stream>>>(bufHb, row_start, pk2, dsq, b3, bufO);

    // ---- layer 4: 64 -> 64 MFMA (same W3/b3, no relu) -> emb in bufO ----
    k_gemm_mfma<64, false, true><<<dim3(1, gy), 256, 0, stream>>>(
        bufO, W3, bufHb, NN, 64, 64, nullptr, nullptr, nullptr, dsq);
    k_agg64_b<false><<<nblkNode, 256, 0, stream>>>(bufHb, row_start, pk2, dsq, b3, bufO);

    // ---- edge MLP, factored layer 1 -> bf16 A/B buffers (MFMA, unscaled) ----
    unsigned short* Abuf = bufHb;                     // NN*64 ushort
    unsigned short* Bbuf = bufHb + (size_t)NN * 64;   // NN*64 ushort
    k_gemm_mfma<64, false, false><<<dim3(1, gy), 256, 0, stream>>>(
        bufO, We1, Abuf, NN, 64, 64, nullptr, nullptr, nullptr, nullptr);
    k_gemm_mfma<64, false, false><<<dim3(1, gy), 256, 0, stream>>>(
        bufO, We1 + (size_t)64 * 64, Bbuf, NN, 64, 64, nullptr, nullptr, nullptr, nullptr);
    k_edge_mlp4<<<(NE + EB - 1) / EB, EB, 0, stream>>>(Abuf, Bbuf, src, dst, bme1, We2, bme2, We3, bme3, out);

    (void)in_sizes; (void)n_in; (void)out_size; (void)ws_size;
}

// Round 14
// 536.406 us; speedup vs baseline: 2.1735x; 1.0491x over previous
//
#include <hip/hip_runtime.h>
#include <hip/hip_bf16.h>
#include <cstddef>

#define NN 50000
#define NE 800000
#define NPAD 50176
#define SCAN_BLOCKS 196   // ceil(NN/256)
#define BN_EPS 1e-5f
#define EB 256            // edges per block in edge MLP (4 waves)

typedef __bf16 bf16x8f __attribute__((ext_vector_type(8)));
typedef unsigned short u16x8 __attribute__((ext_vector_type(8)));
typedef float f32x4 __attribute__((ext_vector_type(4)));

__device__ __forceinline__ unsigned short f2bf(float f) {
    __hip_bfloat16 h = __float2bfloat16(f);
    return *reinterpret_cast<unsigned short*>(&h);
}
__device__ __forceinline__ float bf2f(unsigned short u) {
    return __uint_as_float(((unsigned int)u) << 16);
}

// ---------------- CSR build ----------------
__global__ __launch_bounds__(256) void k_count_int(const int* __restrict__ dst,
                                                   int* __restrict__ cnt) {
    int e = blockIdx.x * 256 + threadIdx.x;
    if (e < NE) atomicAdd(&cnt[dst[e]], 1);
}

__global__ __launch_bounds__(256) void k_bsum(const int* __restrict__ cnt,
                                              int* __restrict__ bsum) {
    __shared__ int red[4];
    int i = blockIdx.x * 256 + threadIdx.x;
    int v = (i < NN) ? cnt[i] : 0;
    #pragma unroll
    for (int off = 32; off > 0; off >>= 1) v += __shfl_down(v, off, 64);
    int lane = threadIdx.x & 63, w = threadIdx.x >> 6;
    if (lane == 0) red[w] = v;
    __syncthreads();
    if (threadIdx.x == 0) bsum[blockIdx.x] = red[0] + red[1] + red[2] + red[3];
}

__global__ __launch_bounds__(256) void k_scan_bsum(int* __restrict__ bsum) {
    __shared__ int tmp[256];
    int t = threadIdx.x;
    int v = (t < SCAN_BLOCKS) ? bsum[t] : 0;
    tmp[t] = v;
    __syncthreads();
    #pragma unroll
    for (int off = 1; off < 256; off <<= 1) {
        int u = (t >= off) ? tmp[t - off] : 0;
        __syncthreads();
        tmp[t] += u;
        __syncthreads();
    }
    if (t < SCAN_BLOCKS) bsum[t] = tmp[t] - v;  // exclusive
}

__global__ __launch_bounds__(256) void k_scan_fin(const int* __restrict__ cnt,
                                                  const int* __restrict__ bsum,
                                                  int* __restrict__ row_start,
                                                  int* __restrict__ cursor,
                                                  float* __restrict__ dsq) {
    __shared__ int tmp[256];
    int t = threadIdx.x;
    int i = blockIdx.x * 256 + t;
    int c = (i < NN) ? cnt[i] : 0;
    tmp[t] = c;
    __syncthreads();
    #pragma unroll
    for (int off = 1; off < 256; off <<= 1) {
        int u = (t >= off) ? tmp[t - off] : 0;
        __syncthreads();
        tmp[t] += u;
        __syncthreads();
    }
    int excl = tmp[t] - c + bsum[blockIdx.x];
    if (i < NN) {
        row_start[i] = excl;
        cursor[i] = excl;
        dsq[i] = rsqrtf((float)c + 1.0f);
    }
    if (i == 0) row_start[NN] = NE;
}

// fill compact CSR entries: src as ushort (NN < 65536)
__global__ __launch_bounds__(256) void k_fill(const int* __restrict__ src,
                                              const int* __restrict__ dst,
                                              int* __restrict__ cursor,
                                              unsigned short* __restrict__ pk2) {
    int e = blockIdx.x * 256 + threadIdx.x;
    if (e < NE) {
        int pos = atomicAdd(&cursor[dst[e]], 1);
        pk2[pos] = (unsigned short)src[e];
    }
}

// ---------------- MFMA bf16 GEMM: C(bf16) = A(f32) @ B(f32) ----------------
template <int BNT, bool BNA, bool SCALE>
__global__ __launch_bounds__(256) void k_gemm_mfma(const float* __restrict__ A,
                                                   const float* __restrict__ B,
                                                   unsigned short* __restrict__ Cb,
                                                   int M, int K, int N,
                                                   const float* __restrict__ stats,
                                                   const float* __restrict__ g,
                                                   const float* __restrict__ be,
                                                   const float* __restrict__ dsq) {
    __shared__ unsigned short As[128 * 56];
    __shared__ unsigned short Bs[BNT * 56];
    const int tid = threadIdx.x;
    const int lane = tid & 63, wave = tid >> 6;
    const int row0 = blockIdx.y * 128, col0 = blockIdx.x * BNT;
    constexpr int NCT = BNT / 16;

    f32x4 acc[2][NCT] = {};

    const int r16 = lane & 15;
    const int kg = (lane >> 4) * 8;

    for (int k0 = 0; k0 < K; k0 += 32) {
        {
            int row = tid >> 1;
            int kh = (tid & 1) * 16;
            int gr = row0 + row;
            unsigned short tmp[16];
            if (gr < M) {
                const float* ap = A + (size_t)gr * K + k0 + kh;
                #pragma unroll
                for (int j = 0; j < 16; ++j) {
                    float v = ap[j];
                    if constexpr (BNA) {
                        int c = k0 + kh + j;
                        v = fmaxf((v - stats[c]) * stats[K + c] * g[c] + be[c], 0.0f);
                    }
                    tmp[j] = f2bf(v);
                }
            } else {
                #pragma unroll
                for (int j = 0; j < 16; ++j) tmp[j] = 0;
            }
            unsigned short* dp = &As[row * 56 + kh];
            *reinterpret_cast<u16x8*>(dp) = *reinterpret_cast<const u16x8*>(&tmp[0]);
            *reinterpret_cast<u16x8*>(dp + 8) = *reinterpret_cast<const u16x8*>(&tmp[8]);
        }
        {
            constexpr int JC = (BNT == 128) ? 16 : 8;
            int col = tid & (BNT - 1);
            int kh = (tid / BNT) * JC;
            unsigned short tmp[JC];
            #pragma unroll
            for (int j = 0; j < JC; ++j)
                tmp[j] = f2bf(B[(size_t)(k0 + kh + j) * N + col0 + col]);
            unsigned short* dp = &Bs[col * 56 + kh];
            #pragma unroll
            for (int j = 0; j < JC; j += 8)
                *reinterpret_cast<u16x8*>(dp + j) = *reinterpret_cast<const u16x8*>(&tmp[j]);
        }
        __syncthreads();

        bf16x8f af[2];
        bf16x8f bfr[NCT];
        #pragma unroll
        for (int rt = 0; rt < 2; ++rt)
            af[rt] = __builtin_bit_cast(bf16x8f,
                *reinterpret_cast<const u16x8*>(&As[(wave * 32 + rt * 16 + r16) * 56 + kg]));
        #pragma unroll
        for (int ct = 0; ct < NCT; ++ct)
            bfr[ct] = __builtin_bit_cast(bf16x8f,
                *reinterpret_cast<const u16x8*>(&Bs[(ct * 16 + r16) * 56 + kg]));
        #pragma unroll
        for (int rt = 0; rt < 2; ++rt)
            #pragma unroll
            for (int ct = 0; ct < NCT; ++ct)
                acc[rt][ct] = __builtin_amdgcn_mfma_f32_16x16x32_bf16(af[rt], bfr[ct], acc[rt][ct], 0, 0, 0);
        __syncthreads();
    }

    const int rg = (lane >> 4) * 4;
    #pragma unroll
    for (int rt = 0; rt < 2; ++rt) {
        #pragma unroll
        for (int r = 0; r < 4; ++r) {
            int gr = row0 + wave * 32 + rt * 16 + rg + r;
            if (gr < M) {
                float sc = 1.0f;
                if constexpr (SCALE) sc = dsq[gr];
                #pragma unroll
                for (int ct = 0; ct < NCT; ++ct)
                    Cb[(size_t)gr * N + col0 + ct * 16 + r16] = f2bf(acc[rt][ct][r] * sc);
            }
        }
    }
}

// ---------------- CSR aggregation, D=256, bf16 rows (pre-scaled by dsq), pure sum ----
__global__ __launch_bounds__(256) void k_agg256_b(const unsigned short* __restrict__ hb,
                                                  const int* __restrict__ row_start,
                                                  const unsigned short* __restrict__ pk2,
                                                  const float* __restrict__ dsq,
                                                  const float* __restrict__ b,
                                                  float* __restrict__ out) {
    int d = blockIdx.x * 4 + (threadIdx.x >> 6);
    if (d >= NN) return;
    int lane = threadIdx.x & 63;
    int rs = row_start[d], re = row_start[d + 1];
    float4 acc0 = make_float4(0.f, 0.f, 0.f, 0.f);
    float4 acc1 = make_float4(0.f, 0.f, 0.f, 0.f);
    int j = rs;
    for (; j + 2 <= re; j += 2) {
        int s0 = (int)pk2[j];
        int s1 = (int)pk2[j + 1];
        ushort4 v0 = *reinterpret_cast<const ushort4*>(hb + (size_t)s0 * 256 + lane * 4);
        ushort4 v1 = *reinterpret_cast<const ushort4*>(hb + (size_t)s1 * 256 + lane * 4);
        acc0.x += bf2f(v0.x); acc0.y += bf2f(v0.y); acc0.z += bf2f(v0.z); acc0.w += bf2f(v0.w);
        acc1.x += bf2f(v1.x); acc1.y += bf2f(v1.y); acc1.z += bf2f(v1.z); acc1.w += bf2f(v1.w);
    }
    if (j < re) {
        int s0 = (int)pk2[j];
        ushort4 v0 = *reinterpret_cast<const ushort4*>(hb + (size_t)s0 * 256 + lane * 4);
        acc0.x += bf2f(v0.x); acc0.y += bf2f(v0.y); acc0.z += bf2f(v0.z); acc0.w += bf2f(v0.w);
    }
    float sd = dsq[d];
    ushort4 hv = *reinterpret_cast<const ushort4*>(hb + (size_t)d * 256 + lane * 4);
    float4 bv = *reinterpret_cast<const float4*>(b + lane * 4);
    float4 o;
    o.x = fmaf(sd, acc0.x + acc1.x + bf2f(hv.x), bv.x);
    o.y = fmaf(sd, acc0.y + acc1.y + bf2f(hv.y), bv.y);
    o.z = fmaf(sd, acc0.z + acc1.z + bf2f(hv.z), bv.z);
    o.w = fmaf(sd, acc0.w + acc1.w + bf2f(hv.w), bv.w);
    *reinterpret_cast<float4*>(out + (size_t)d * 256 + lane * 4) = o;
}

// ---------------- CSR aggregation, D=64, bf16 rows (pre-scaled), pure sum ----------------
template <bool RELU>
__global__ __launch_bounds__(256) void k_agg64_b(const unsigned short* __restrict__ hb,
                                                 const int* __restrict__ row_start,
                                                 const unsigned short* __restrict__ pk2,
                                                 const float* __restrict__ dsq,
                                                 const float* __restrict__ b,
                                                 float* __restrict__ out) {
    int d = blockIdx.x * 4 + (threadIdx.x >> 6);
    if (d >= NN) return;
    int lane = threadIdx.x & 63;
    int rs = row_start[d], re = row_start[d + 1];
    float acc0 = 0.0f, acc1 = 0.0f;
    int j = rs;
    for (; j + 2 <= re; j += 2) {
        int s0 = (int)pk2[j];
        int s1 = (int)pk2[j + 1];
        acc0 += bf2f(hb[(size_t)s0 * 64 + lane]);
        acc1 += bf2f(hb[(size_t)s1 * 64 + lane]);
    }
    if (j < re) {
        int s0 = (int)pk2[j];
        acc0 += bf2f(hb[(size_t)s0 * 64 + lane]);
    }
    float o = fmaf(dsq[d], acc0 + acc1 + bf2f(hb[(size_t)d * 64 + lane]), b[lane]);
    if (RELU) o = fmaxf(o, 0.0f);
    out[(size_t)d * 64 + lane] = o;
}

// ---------------- BatchNorm stats ----------------
template <int C>
__global__ __launch_bounds__(256) void k_bn_stats(const float* __restrict__ x,
                                                  float* __restrict__ stats) {
    int c = threadIdx.x & (C - 1);
    int rstart = blockIdx.x * (256 / C) + (threadIdx.x / C);
    int rstride = gridDim.x * (256 / C);
    float s = 0.0f, ss = 0.0f;
    for (int r = rstart; r < NN; r += rstride) {
        float v = x[(size_t)r * C + c];
        s += v;
        ss += v * v;
    }
    atomicAdd(&stats[c], s);
    atomicAdd(&stats[C + c], ss);
}

__global__ __launch_bounds__(256) void k_bn_fin(float* __restrict__ stats, int C) {
    int c = threadIdx.x;
    if (c < C) {
        const float invN = 1.0f / (float)NN;
        float mean = stats[c] * invN;
        float var = stats[C + c] * invN - mean * mean;
        stats[c] = mean;
        stats[C + c] = rsqrtf(var + BN_EPS);
    }
}

// ---------------- edge MLP v5: phase1 gather -> bf16 LDS; phase2 MFMA 64->32; 32->2 VALU ----
__global__ __launch_bounds__(EB) void k_edge_mlp5(const unsigned short* __restrict__ A,
                                                  const unsigned short* __restrict__ B,
                                                  const int* __restrict__ src,
                                                  const int* __restrict__ dst,
                                                  const float* __restrict__ b1,
                                                  const float* __restrict__ W2,
                                                  const float* __restrict__ b2,
                                                  const float* __restrict__ W3,
                                                  const float* __restrict__ b3,
                                                  float* __restrict__ out) {
    __shared__ unsigned short h1s[EB * 72];      // [edge][k] stride 72 (144B, 16B-aligned)
    __shared__ unsigned short Bs_hi[32 * 72];    // W2^T hi  [col][k]
    __shared__ unsigned short Bs_lo[32 * 72];    // W2^T residual
    const int tid = threadIdx.x;
    const int w = tid >> 6, lane = tid & 63;
    const int base = blockIdx.x * EB + w * 64;

    // ---- stage W2 as bf16 hi + lo residual, transposed [32 cols][64 k] ----
    {
        int col = tid & 31;
        int k8 = (tid >> 5) * 8;
        #pragma unroll
        for (int j = 0; j < 8; ++j) {
            float v = W2[(size_t)(k8 + j) * 32 + col];
            unsigned short hi = f2bf(v);
            float res = v - bf2f(hi);
            Bs_hi[col * 72 + k8 + j] = hi;
            Bs_lo[col * 72 + k8 + j] = f2bf(res);
        }
    }

    // ---- phase 1: gather h1 = relu(A[s]+B[d]+b1) -> LDS (wave-local rows) ----
    int ee = base + lane;
    if (ee >= NE) ee = NE - 1;
    int se = src[ee];
    int de = dst[ee];

    const int eh = lane >> 5;
    const int ch2 = (lane & 31) * 2;
    const float b1v0 = b1[ch2], b1v1 = b1[ch2 + 1];

    #pragma unroll 4
    for (int i = 0; i < 32; ++i) {
        int ei = 2 * i + eh;
        int s = __shfl(se, ei, 64);
        int d = __shfl(de, ei, 64);
        ushort2 ua = *reinterpret_cast<const ushort2*>(A + (size_t)s * 64 + ch2);
        ushort2 ub = *reinterpret_cast<const ushort2*>(B + (size_t)d * 64 + ch2);
        float v0 = fmaxf(bf2f(ua.x) + bf2f(ub.x) + b1v0, 0.0f);
        float v1 = fmaxf(bf2f(ua.y) + bf2f(ub.y) + b1v1, 0.0f);
        ushort2 uo;
        uo.x = f2bf(v0);
        uo.y = f2bf(v1);
        *reinterpret_cast<ushort2*>(&h1s[(w * 64 + ei) * 72 + ch2]) = uo;
    }
    __syncthreads();   // for Bs_hi/Bs_lo (h1s rows are wave-local)

    // ---- phase 2: h2 = relu(h1 @ W2 + b2) via MFMA; out = h2 @ W3 + b3 ----
    const int r16 = lane & 15;
    const int kg = (lane >> 4) * 8;
    const int rg = (lane >> 4) * 4;

    const float b2c0 = b2[r16], b2c1 = b2[16 + r16];
    const float w300 = W3[r16 * 2], w301 = W3[r16 * 2 + 1];
    const float w310 = W3[(16 + r16) * 2], w311 = W3[(16 + r16) * 2 + 1];
    const float b30 = b3[0], b31 = b3[1];

    bf16x8f b0h[2], b0l[2], b1h[2], b1l[2];
    #pragma unroll
    for (int ks = 0; ks < 2; ++ks) {
        b0h[ks] = __builtin_bit_cast(bf16x8f, *reinterpret_cast<const u16x8*>(&Bs_hi[r16 * 72 + ks * 32 + kg]));
        b0l[ks] = __builtin_bit_cast(bf16x8f, *reinterpret_cast<const u16x8*>(&Bs_lo[r16 * 72 + ks * 32 + kg]));
        b1h[ks] = __builtin_bit_cast(bf16x8f, *reinterpret_cast<const u16x8*>(&Bs_hi[(16 + r16) * 72 + ks * 32 + kg]));
        b1l[ks] = __builtin_bit_cast(bf16x8f, *reinterpret_cast<const u16x8*>(&Bs_lo[(16 + r16) * 72 + ks * 32 + kg]));
    }

    #pragma unroll
    for (int rt = 0; rt < 4; ++rt) {
        f32x4 acc0 = {}, acc1 = {};
        #pragma unroll
        for (int ks = 0; ks < 2; ++ks) {
            bf16x8f af = __builtin_bit_cast(bf16x8f,
                *reinterpret_cast<const u16x8*>(&h1s[(w * 64 + rt * 16 + r16) * 72 + ks * 32 + kg]));
            acc0 = __builtin_amdgcn_mfma_f32_16x16x32_bf16(af, b0h[ks], acc0, 0, 0, 0);
            acc0 = __builtin_amdgcn_mfma_f32_16x16x32_bf16(af, b0l[ks], acc0, 0, 0, 0);
            acc1 = __builtin_amdgcn_mfma_f32_16x16x32_bf16(af, b1h[ks], acc1, 0, 0, 0);
            acc1 = __builtin_amdgcn_mfma_f32_16x16x32_bf16(af, b1l[ks], acc1, 0, 0, 0);
        }
        #pragma unroll
        for (int r = 0; r < 4; ++r) {
            float h20 = fmaxf(acc0[r] + b2c0, 0.0f);
            float h21 = fmaxf(acc1[r] + b2c1, 0.0f);
            float p0 = fmaf(h20, w300, h21 * w310);
            float p1 = fmaf(h20, w301, h21 * w311);
            p0 += __shfl_xor(p0, 1, 64); p0 += __shfl_xor(p0, 2, 64);
            p0 += __shfl_xor(p0, 4, 64); p0 += __shfl_xor(p0, 8, 64);
            p1 += __shfl_xor(p1, 1, 64); p1 += __shfl_xor(p1, 2, 64);
            p1 += __shfl_xor(p1, 4, 64); p1 += __shfl_xor(p1, 8, 64);
            if (r16 == 0) {
                int e = base + rt * 16 + rg + r;
                if (e < NE)
                    *reinterpret_cast<float2*>(out + (size_t)2 * e) = make_float2(p0 + b30, p1 + b31);
            }
        }
    }
}

// ---------------- launch ----------------
extern "C" void kernel_launch(void* const* d_in, const int* in_sizes, int n_in,
                              void* d_out, int out_size, void* d_ws, size_t ws_size,
                              hipStream_t stream) {
    const float* x    = (const float*)d_in[0];
    const int*   ei   = (const int*)d_in[1];
    const int*   src  = ei;
    const int*   dst  = ei + NE;
    const float* W1   = (const float*)d_in[2];
    const float* b1   = (const float*)d_in[3];
    const float* g1   = (const float*)d_in[4];
    const float* be1  = (const float*)d_in[5];
    const float* W2   = (const float*)d_in[6];
    const float* b2   = (const float*)d_in[7];
    const float* g2   = (const float*)d_in[8];
    const float* be2  = (const float*)d_in[9];
    const float* W3   = (const float*)d_in[10];
    const float* b3   = (const float*)d_in[11];
    const float* We1  = (const float*)d_in[12];
    const float* bme1 = (const float*)d_in[13];
    const float* We2  = (const float*)d_in[14];
    const float* bme2 = (const float*)d_in[15];
    const float* We3  = (const float*)d_in[16];
    const float* bme3 = (const float*)d_in[17];
    float* out = (float*)d_out;
    char* ws = (char*)d_ws;

    float* dsq      = (float*)ws;                         ws += NPAD * 4;
    float* stats    = (float*)ws;                         ws += 1024 * 4;
    int*   cnt      = (int*)ws;                           ws += NPAD * 4;
    int*   cursor   = (int*)ws;                           ws += NPAD * 4;
    int*   bsum     = (int*)ws;                           ws += 256 * 4;
    int*   row_start= (int*)ws;                           ws += (NPAD + 16) * 4;
    unsigned short* pk2 = (unsigned short*)ws;            ws += (size_t)NE * 2;
    ws += 64;  // alignment pad
    unsigned short* bufHb = (unsigned short*)ws;          ws += (size_t)NN * 256 * 2;
    float* bufO     = (float*)ws;                         ws += (size_t)NN * 256 * 4;

    const int nblkE = (NE + 255) / 256;
    const int nblkNode = (NN + 3) / 4;
    const int gy = (NN + 127) / 128;   // 391

    // ---- CSR build + degree terms ----
    hipMemsetAsync(cnt, 0, NPAD * sizeof(int), stream);
    k_count_int<<<nblkE, 256, 0, stream>>>(dst, cnt);
    k_bsum<<<SCAN_BLOCKS, 256, 0, stream>>>(cnt, bsum);
    k_scan_bsum<<<1, 256, 0, stream>>>(bsum);
    k_scan_fin<<<SCAN_BLOCKS, 256, 0, stream>>>(cnt, bsum, row_start, cursor, dsq);
    k_fill<<<nblkE, 256, 0, stream>>>(src, dst, cursor, pk2);

    // ---- layer 1: 256 -> 256 MFMA (bf16+dsq-scaled out), agg, BN stats ----
    k_gemm_mfma<128, false, true><<<dim3(2, gy), 256, 0, stream>>>(
        x, W1, bufHb, NN, 256, 256, nullptr, nullptr, nullptr, dsq);
    k_agg256_b<<<nblkNode, 256, 0, stream>>>(bufHb, row_start, pk2, dsq, b1, bufO);
    hipMemsetAsync(stats, 0, 1024 * sizeof(float), stream);
    k_bn_stats<256><<<256, 256, 0, stream>>>(bufO, stats);
    k_bn_fin<<<1, 256, 0, stream>>>(stats, 256);

    // ---- layer 2: A = BN1(bufO) fused; 256 -> 64 MFMA; agg; BN2 stats ----
    k_gemm_mfma<64, true, true><<<dim3(1, gy), 256, 0, stream>>>(
        bufO, W2, bufHb, NN, 256, 64, stats, g1, be1, dsq);
    k_agg64_b<false><<<nblkNode, 256, 0, stream>>>(bufHb, row_start, pk2, dsq, b2, bufO);
    hipMemsetAsync(stats, 0, 1024 * sizeof(float), stream);
    k_bn_stats<64><<<256, 256, 0, stream>>>(bufO, stats);
    k_bn_fin<<<1, 256, 0, stream>>>(stats, 64);

    // ---- layer 3: A = BN2(bufO) fused; 64 -> 64 MFMA; agg + relu ----
    k_gemm_mfma<64, true, true><<<dim3(1, gy), 256, 0, stream>>>(
        bufO, W3, bufHb, NN, 64, 64, stats, g2, be2, dsq);
    k_agg64_b<true><<<nblkNode, 256, 0, stream>>>(bufHb, row_start, pk2, dsq, b3, bufO);

    // ---- layer 4: 64 -> 64 MFMA (same W3/b3, no relu) -> emb in bufO ----
    k_gemm_mfma<64, false, true><<<dim3(1, gy), 256, 0, stream>>>(
        bufO, W3, bufHb, NN, 64, 64, nullptr, nullptr, nullptr, dsq);
    k_agg64_b<false><<<nblkNode, 256, 0, stream>>>(bufHb, row_start, pk2, dsq, b3, bufO);

    // ---- edge MLP, factored layer 1 -> bf16 A/B buffers (MFMA, unscaled) ----
    unsigned short* Abuf = bufHb;                     // NN*64 ushort
    unsigned short* Bbuf = bufHb + (size_t)NN * 64;   // NN*64 ushort
    k_gemm_mfma<64, false, false><<<dim3(1, gy), 256, 0, stream>>>(
        bufO, We1, Abuf, NN, 64, 64, nullptr, nullptr, nullptr, nullptr);
    k_gemm_mfma<64, false, false><<<dim3(1, gy), 256, 0, stream>>>(
        bufO, We1 + (size_t)64 * 64, Bbuf, NN, 64, 64, nullptr, nullptr, nullptr, nullptr);
    k_edge_mlp5<<<(NE + EB - 1) / EB, EB, 0, stream>>>(Abuf, Bbuf, src, dst, bme1, We2, bme2, We3, bme3, out);

    (void)in_sizes; (void)n_in; (void)out_size; (void)ws_size;
}

// Round 15
// 478.204 us; speedup vs baseline: 2.4380x; 1.1217x over previous
//
#include <hip/hip_runtime.h>
#include <hip/hip_bf16.h>
#include <cstddef>

#define NN 50000
#define NE 800000
#define NPAD 50176
#define SCAN_BLOCKS 196   // ceil(NN/256)
#define BN_EPS 1e-5f
#define EB 256            // edges per block in edge MLP (4 waves)

typedef __bf16 bf16x8f __attribute__((ext_vector_type(8)));
typedef unsigned short u16x8 __attribute__((ext_vector_type(8)));
typedef float f32x4 __attribute__((ext_vector_type(4)));

__device__ __forceinline__ unsigned short f2bf(float f) {
    __hip_bfloat16 h = __float2bfloat16(f);
    return *reinterpret_cast<unsigned short*>(&h);
}
__device__ __forceinline__ float bf2f(unsigned short u) {
    return __uint_as_float(((unsigned int)u) << 16);
}

// ---------------- CSR build ----------------
__global__ __launch_bounds__(256) void k_count_int(const int* __restrict__ dst,
                                                   int* __restrict__ cnt) {
    int e = blockIdx.x * 256 + threadIdx.x;
    if (e < NE) atomicAdd(&cnt[dst[e]], 1);
}

__global__ __launch_bounds__(256) void k_bsum(const int* __restrict__ cnt,
                                              int* __restrict__ bsum) {
    __shared__ int red[4];
    int i = blockIdx.x * 256 + threadIdx.x;
    int v = (i < NN) ? cnt[i] : 0;
    #pragma unroll
    for (int off = 32; off > 0; off >>= 1) v += __shfl_down(v, off, 64);
    int lane = threadIdx.x & 63, w = threadIdx.x >> 6;
    if (lane == 0) red[w] = v;
    __syncthreads();
    if (threadIdx.x == 0) bsum[blockIdx.x] = red[0] + red[1] + red[2] + red[3];
}

__global__ __launch_bounds__(256) void k_scan_bsum(int* __restrict__ bsum) {
    __shared__ int tmp[256];
    int t = threadIdx.x;
    int v = (t < SCAN_BLOCKS) ? bsum[t] : 0;
    tmp[t] = v;
    __syncthreads();
    #pragma unroll
    for (int off = 1; off < 256; off <<= 1) {
        int u = (t >= off) ? tmp[t - off] : 0;
        __syncthreads();
        tmp[t] += u;
        __syncthreads();
    }
    if (t < SCAN_BLOCKS) bsum[t] = tmp[t] - v;  // exclusive
}

__global__ __launch_bounds__(256) void k_scan_fin(const int* __restrict__ cnt,
                                                  const int* __restrict__ bsum,
                                                  int* __restrict__ row_start,
                                                  int* __restrict__ cursor,
                                                  float* __restrict__ dsq) {
    __shared__ int tmp[256];
    int t = threadIdx.x;
    int i = blockIdx.x * 256 + t;
    int c = (i < NN) ? cnt[i] : 0;
    tmp[t] = c;
    __syncthreads();
    #pragma unroll
    for (int off = 1; off < 256; off <<= 1) {
        int u = (t >= off) ? tmp[t - off] : 0;
        __syncthreads();
        tmp[t] += u;
        __syncthreads();
    }
    int excl = tmp[t] - c + bsum[blockIdx.x];
    if (i < NN) {
        row_start[i] = excl;
        cursor[i] = excl;
        dsq[i] = rsqrtf((float)c + 1.0f);
    }
    if (i == 0) row_start[NN] = NE;
}

// fill compact CSR entries: src as ushort (NN < 65536)
__global__ __launch_bounds__(256) void k_fill(const int* __restrict__ src,
                                              const int* __restrict__ dst,
                                              int* __restrict__ cursor,
                                              unsigned short* __restrict__ pk2) {
    int e = blockIdx.x * 256 + threadIdx.x;
    if (e < NE) {
        int pos = atomicAdd(&cursor[dst[e]], 1);
        pk2[pos] = (unsigned short)src[e];
    }
}

// ---------------- MFMA bf16 GEMM: C(bf16) = A(f32) @ B(f32) ----------------
// FUSEB: B is We1[128][64]; fused N=128 output, col<64 -> We1[k][col], col>=64 -> We1[64+k][col-64]
template <int BNT, bool BNA, bool SCALE, bool FUSEB = false>
__global__ __launch_bounds__(256) void k_gemm_mfma(const float* __restrict__ A,
                                                   const float* __restrict__ B,
                                                   unsigned short* __restrict__ Cb,
                                                   int M, int K, int N,
                                                   const float* __restrict__ stats,
                                                   const float* __restrict__ g,
                                                   const float* __restrict__ be,
                                                   const float* __restrict__ dsq) {
    __shared__ unsigned short As[128 * 56];
    __shared__ unsigned short Bs[BNT * 56];
    const int tid = threadIdx.x;
    const int lane = tid & 63, wave = tid >> 6;
    const int row0 = blockIdx.y * 128, col0 = blockIdx.x * BNT;
    constexpr int NCT = BNT / 16;

    f32x4 acc[2][NCT] = {};

    const int r16 = lane & 15;
    const int kg = (lane >> 4) * 8;

    for (int k0 = 0; k0 < K; k0 += 32) {
        {
            int row = tid >> 1;
            int kh = (tid & 1) * 16;
            int gr = row0 + row;
            unsigned short tmp[16];
            if (gr < M) {
                const float* ap = A + (size_t)gr * K + k0 + kh;
                #pragma unroll
                for (int j = 0; j < 16; ++j) {
                    float v = ap[j];
                    if constexpr (BNA) {
                        int c = k0 + kh + j;
                        v = fmaxf((v - stats[c]) * stats[K + c] * g[c] + be[c], 0.0f);
                    }
                    tmp[j] = f2bf(v);
                }
            } else {
                #pragma unroll
                for (int j = 0; j < 16; ++j) tmp[j] = 0;
            }
            unsigned short* dp = &As[row * 56 + kh];
            *reinterpret_cast<u16x8*>(dp) = *reinterpret_cast<const u16x8*>(&tmp[0]);
            *reinterpret_cast<u16x8*>(dp + 8) = *reinterpret_cast<const u16x8*>(&tmp[8]);
        }
        {
            constexpr int JC = (BNT == 128) ? 16 : 8;
            int col = tid & (BNT - 1);
            int kh = (tid / BNT) * JC;
            unsigned short tmp[JC];
            #pragma unroll
            for (int j = 0; j < JC; ++j) {
                float bv;
                if constexpr (FUSEB) {
                    int kk = k0 + kh + j;
                    int c = col0 + col;
                    bv = (c < 64) ? B[(size_t)kk * 64 + c]
                                  : B[(size_t)(64 + kk) * 64 + (c - 64)];
                } else {
                    bv = B[(size_t)(k0 + kh + j) * N + col0 + col];
                }
                tmp[j] = f2bf(bv);
            }
            unsigned short* dp = &Bs[col * 56 + kh];
            #pragma unroll
            for (int j = 0; j < JC; j += 8)
                *reinterpret_cast<u16x8*>(dp + j) = *reinterpret_cast<const u16x8*>(&tmp[j]);
        }
        __syncthreads();

        bf16x8f af[2];
        bf16x8f bfr[NCT];
        #pragma unroll
        for (int rt = 0; rt < 2; ++rt)
            af[rt] = __builtin_bit_cast(bf16x8f,
                *reinterpret_cast<const u16x8*>(&As[(wave * 32 + rt * 16 + r16) * 56 + kg]));
        #pragma unroll
        for (int ct = 0; ct < NCT; ++ct)
            bfr[ct] = __builtin_bit_cast(bf16x8f,
                *reinterpret_cast<const u16x8*>(&Bs[(ct * 16 + r16) * 56 + kg]));
        #pragma unroll
        for (int rt = 0; rt < 2; ++rt)
            #pragma unroll
            for (int ct = 0; ct < NCT; ++ct)
                acc[rt][ct] = __builtin_amdgcn_mfma_f32_16x16x32_bf16(af[rt], bfr[ct], acc[rt][ct], 0, 0, 0);
        __syncthreads();
    }

    const int rg = (lane >> 4) * 4;
    #pragma unroll
    for (int rt = 0; rt < 2; ++rt) {
        #pragma unroll
        for (int r = 0; r < 4; ++r) {
            int gr = row0 + wave * 32 + rt * 16 + rg + r;
            if (gr < M) {
                float sc = 1.0f;
                if constexpr (SCALE) sc = dsq[gr];
                #pragma unroll
                for (int ct = 0; ct < NCT; ++ct)
                    Cb[(size_t)gr * N + col0 + ct * 16 + r16] = f2bf(acc[rt][ct][r] * sc);
            }
        }
    }
}

// ---------------- CSR aggregation, D=256: half-wave per edge, u16x8 lanes ----------------
__global__ __launch_bounds__(256) void k_agg256_b(const unsigned short* __restrict__ hb,
                                                  const int* __restrict__ row_start,
                                                  const unsigned short* __restrict__ pk2,
                                                  const float* __restrict__ dsq,
                                                  const float* __restrict__ b,
                                                  float* __restrict__ out) {
    int d = blockIdx.x * 4 + (threadIdx.x >> 6);
    if (d >= NN) return;
    const int lane = threadIdx.x & 63;
    const int eh = lane >> 5;          // half index: edge slot
    const int ch8 = (lane & 31) * 8;   // channel base (8 bf16 per lane)
    int rs = row_start[d], re = row_start[d + 1];
    float a0[8] = {}, a1[8] = {};
    int j = rs;
    for (; j + 4 <= re; j += 4) {
        int s0 = (int)pk2[j + eh];
        int s1 = (int)pk2[j + 2 + eh];
        u16x8 v0 = *reinterpret_cast<const u16x8*>(hb + (size_t)s0 * 256 + ch8);
        u16x8 v1 = *reinterpret_cast<const u16x8*>(hb + (size_t)s1 * 256 + ch8);
        #pragma unroll
        for (int t = 0; t < 8; ++t) { a0[t] += bf2f(v0[t]); a1[t] += bf2f(v1[t]); }
    }
    for (; j < re; j += 2) {
        int idx = j + eh;
        if (idx < re) {
            int s0 = (int)pk2[idx];
            u16x8 v0 = *reinterpret_cast<const u16x8*>(hb + (size_t)s0 * 256 + ch8);
            #pragma unroll
            for (int t = 0; t < 8; ++t) a0[t] += bf2f(v0[t]);
        }
    }
    #pragma unroll
    for (int t = 0; t < 8; ++t) {
        a0[t] += a1[t];
        a0[t] += __shfl_xor(a0[t], 32, 64);
    }
    if (eh == 0) {
        float sd = dsq[d];
        u16x8 hv = *reinterpret_cast<const u16x8*>(hb + (size_t)d * 256 + ch8);
        float4 bv0 = *reinterpret_cast<const float4*>(b + ch8);
        float4 bv1 = *reinterpret_cast<const float4*>(b + ch8 + 4);
        float4 o0, o1;
        o0.x = fmaf(sd, a0[0] + bf2f(hv[0]), bv0.x);
        o0.y = fmaf(sd, a0[1] + bf2f(hv[1]), bv0.y);
        o0.z = fmaf(sd, a0[2] + bf2f(hv[2]), bv0.z);
        o0.w = fmaf(sd, a0[3] + bf2f(hv[3]), bv0.w);
        o1.x = fmaf(sd, a0[4] + bf2f(hv[4]), bv1.x);
        o1.y = fmaf(sd, a0[5] + bf2f(hv[5]), bv1.y);
        o1.z = fmaf(sd, a0[6] + bf2f(hv[6]), bv1.z);
        o1.w = fmaf(sd, a0[7] + bf2f(hv[7]), bv1.w);
        *reinterpret_cast<float4*>(out + (size_t)d * 256 + ch8) = o0;
        *reinterpret_cast<float4*>(out + (size_t)d * 256 + ch8 + 4) = o1;
    }
}

// ---------------- CSR aggregation, D=64: quarter-wave per edge, ushort4 lanes ----------------
template <bool RELU>
__global__ __launch_bounds__(256) void k_agg64_b(const unsigned short* __restrict__ hb,
                                                 const int* __restrict__ row_start,
                                                 const unsigned short* __restrict__ pk2,
                                                 const float* __restrict__ dsq,
                                                 const float* __restrict__ b,
                                                 float* __restrict__ out) {
    int d = blockIdx.x * 4 + (threadIdx.x >> 6);
    if (d >= NN) return;
    const int lane = threadIdx.x & 63;
    const int q = lane >> 4;           // quarter index: edge slot
    const int ch4 = (lane & 15) * 4;   // channel base (4 bf16 per lane)
    int rs = row_start[d], re = row_start[d + 1];
    float a0[4] = {}, a1[4] = {};
    int j = rs;
    for (; j + 8 <= re; j += 8) {
        int s0 = (int)pk2[j + q];
        int s1 = (int)pk2[j + 4 + q];
        ushort4 v0 = *reinterpret_cast<const ushort4*>(hb + (size_t)s0 * 64 + ch4);
        ushort4 v1 = *reinterpret_cast<const ushort4*>(hb + (size_t)s1 * 64 + ch4);
        a0[0] += bf2f(v0.x); a0[1] += bf2f(v0.y); a0[2] += bf2f(v0.z); a0[3] += bf2f(v0.w);
        a1[0] += bf2f(v1.x); a1[1] += bf2f(v1.y); a1[2] += bf2f(v1.z); a1[3] += bf2f(v1.w);
    }
    for (; j < re; j += 4) {
        int idx = j + q;
        if (idx < re) {
            int s0 = (int)pk2[idx];
            ushort4 v0 = *reinterpret_cast<const ushort4*>(hb + (size_t)s0 * 64 + ch4);
            a0[0] += bf2f(v0.x); a0[1] += bf2f(v0.y); a0[2] += bf2f(v0.z); a0[3] += bf2f(v0.w);
        }
    }
    #pragma unroll
    for (int t = 0; t < 4; ++t) {
        a0[t] += a1[t];
        a0[t] += __shfl_xor(a0[t], 16, 64);
        a0[t] += __shfl_xor(a0[t], 32, 64);
    }
    if (q == 0) {
        float sd = dsq[d];
        ushort4 hv = *reinterpret_cast<const ushort4*>(hb + (size_t)d * 64 + ch4);
        float4 bv = *reinterpret_cast<const float4*>(b + ch4);
        float4 o;
        o.x = fmaf(sd, a0[0] + bf2f(hv.x), bv.x);
        o.y = fmaf(sd, a0[1] + bf2f(hv.y), bv.y);
        o.z = fmaf(sd, a0[2] + bf2f(hv.z), bv.z);
        o.w = fmaf(sd, a0[3] + bf2f(hv.w), bv.w);
        if (RELU) {
            o.x = fmaxf(o.x, 0.0f); o.y = fmaxf(o.y, 0.0f);
            o.z = fmaxf(o.z, 0.0f); o.w = fmaxf(o.w, 0.0f);
        }
        *reinterpret_cast<float4*>(out + (size_t)d * 64 + ch4) = o;
    }
}

// ---------------- BatchNorm stats ----------------
template <int C>
__global__ __launch_bounds__(256) void k_bn_stats(const float* __restrict__ x,
                                                  float* __restrict__ stats) {
    int c = threadIdx.x & (C - 1);
    int rstart = blockIdx.x * (256 / C) + (threadIdx.x / C);
    int rstride = gridDim.x * (256 / C);
    float s = 0.0f, ss = 0.0f;
    for (int r = rstart; r < NN; r += rstride) {
        float v = x[(size_t)r * C + c];
        s += v;
        ss += v * v;
    }
    atomicAdd(&stats[c], s);
    atomicAdd(&stats[C + c], ss);
}

__global__ __launch_bounds__(256) void k_bn_fin(float* __restrict__ stats, int C) {
    int c = threadIdx.x;
    if (c < C) {
        const float invN = 1.0f / (float)NN;
        float mean = stats[c] * invN;
        float var = stats[C + c] * invN - mean * mean;
        stats[c] = mean;
        stats[C + c] = rsqrtf(var + BN_EPS);
    }
}

// ---------------- edge MLP v5: AB interleaved [NN][128]; MFMA tail ----------------
__global__ __launch_bounds__(EB) void k_edge_mlp5(const unsigned short* __restrict__ AB,
                                                  const int* __restrict__ src,
                                                  const int* __restrict__ dst,
                                                  const float* __restrict__ b1,
                                                  const float* __restrict__ W2,
                                                  const float* __restrict__ b2,
                                                  const float* __restrict__ W3,
                                                  const float* __restrict__ b3,
                                                  float* __restrict__ out) {
    __shared__ unsigned short h1s[EB * 72];      // [edge][k] stride 72 (144B, 16B-aligned)
    __shared__ unsigned short Bs_hi[32 * 72];    // W2^T hi  [col][k]
    __shared__ unsigned short Bs_lo[32 * 72];    // W2^T residual
    const int tid = threadIdx.x;
    const int w = tid >> 6, lane = tid & 63;
    const int base = blockIdx.x * EB + w * 64;

    // ---- stage W2 as bf16 hi + lo residual, transposed [32 cols][64 k] ----
    {
        int col = tid & 31;
        int k8 = (tid >> 5) * 8;
        #pragma unroll
        for (int j = 0; j < 8; ++j) {
            float v = W2[(size_t)(k8 + j) * 32 + col];
            unsigned short hi = f2bf(v);
            float res = v - bf2f(hi);
            Bs_hi[col * 72 + k8 + j] = hi;
            Bs_lo[col * 72 + k8 + j] = f2bf(res);
        }
    }

    // ---- phase 1: gather h1 = relu(A[s]+B[d]+b1) -> LDS (wave-local rows) ----
    int ee = base + lane;
    if (ee >= NE) ee = NE - 1;
    int se = src[ee];
    int de = dst[ee];

    const int eh = lane >> 5;
    const int ch2 = (lane & 31) * 2;
    const float b1v0 = b1[ch2], b1v1 = b1[ch2 + 1];

    #pragma unroll 4
    for (int i = 0; i < 32; ++i) {
        int ei = 2 * i + eh;
        int s = __shfl(se, ei, 64);
        int d = __shfl(de, ei, 64);
        ushort2 ua = *reinterpret_cast<const ushort2*>(AB + (size_t)s * 128 + ch2);
        ushort2 ub = *reinterpret_cast<const ushort2*>(AB + (size_t)d * 128 + 64 + ch2);
        float v0 = fmaxf(bf2f(ua.x) + bf2f(ub.x) + b1v0, 0.0f);
        float v1 = fmaxf(bf2f(ua.y) + bf2f(ub.y) + b1v1, 0.0f);
        ushort2 uo;
        uo.x = f2bf(v0);
        uo.y = f2bf(v1);
        *reinterpret_cast<ushort2*>(&h1s[(w * 64 + ei) * 72 + ch2]) = uo;
    }
    __syncthreads();   // for Bs_hi/Bs_lo (h1s rows are wave-local)

    // ---- phase 2: h2 = relu(h1 @ W2 + b2) via MFMA; out = h2 @ W3 + b3 ----
    const int r16 = lane & 15;
    const int kg = (lane >> 4) * 8;
    const int rg = (lane >> 4) * 4;

    const float b2c0 = b2[r16], b2c1 = b2[16 + r16];
    const float w300 = W3[r16 * 2], w301 = W3[r16 * 2 + 1];
    const float w310 = W3[(16 + r16) * 2], w311 = W3[(16 + r16) * 2 + 1];
    const float b30 = b3[0], b31 = b3[1];

    bf16x8f b0h[2], b0l[2], b1h[2], b1l[2];
    #pragma unroll
    for (int ks = 0; ks < 2; ++ks) {
        b0h[ks] = __builtin_bit_cast(bf16x8f, *reinterpret_cast<const u16x8*>(&Bs_hi[r16 * 72 + ks * 32 + kg]));
        b0l[ks] = __builtin_bit_cast(bf16x8f, *reinterpret_cast<const u16x8*>(&Bs_lo[r16 * 72 + ks * 32 + kg]));
        b1h[ks] = __builtin_bit_cast(bf16x8f, *reinterpret_cast<const u16x8*>(&Bs_hi[(16 + r16) * 72 + ks * 32 + kg]));
        b1l[ks] = __builtin_bit_cast(bf16x8f, *reinterpret_cast<const u16x8*>(&Bs_lo[(16 + r16) * 72 + ks * 32 + kg]));
    }

    #pragma unroll
    for (int rt = 0; rt < 4; ++rt) {
        f32x4 acc0 = {}, acc1 = {};
        #pragma unroll
        for (int ks = 0; ks < 2; ++ks) {
            bf16x8f af = __builtin_bit_cast(bf16x8f,
                *reinterpret_cast<const u16x8*>(&h1s[(w * 64 + rt * 16 + r16) * 72 + ks * 32 + kg]));
            acc0 = __builtin_amdgcn_mfma_f32_16x16x32_bf16(af, b0h[ks], acc0, 0, 0, 0);
            acc0 = __builtin_amdgcn_mfma_f32_16x16x32_bf16(af, b0l[ks], acc0, 0, 0, 0);
            acc1 = __builtin_amdgcn_mfma_f32_16x16x32_bf16(af, b1h[ks], acc1, 0, 0, 0);
            acc1 = __builtin_amdgcn_mfma_f32_16x16x32_bf16(af, b1l[ks], acc1, 0, 0, 0);
        }
        #pragma unroll
        for (int r = 0; r < 4; ++r) {
            float h20 = fmaxf(acc0[r] + b2c0, 0.0f);
            float h21 = fmaxf(acc1[r] + b2c1, 0.0f);
            float p0 = fmaf(h20, w300, h21 * w310);
            float p1 = fmaf(h20, w301, h21 * w311);
            p0 += __shfl_xor(p0, 1, 64); p0 += __shfl_xor(p0, 2, 64);
            p0 += __shfl_xor(p0, 4, 64); p0 += __shfl_xor(p0, 8, 64);
            p1 += __shfl_xor(p1, 1, 64); p1 += __shfl_xor(p1, 2, 64);
            p1 += __shfl_xor(p1, 4, 64); p1 += __shfl_xor(p1, 8, 64);
            if (r16 == 0) {
                int e = base + rt * 16 + rg + r;
                if (e < NE)
                    *reinterpret_cast<float2*>(out + (size_t)2 * e) = make_float2(p0 + b30, p1 + b31);
            }
        }
    }
}

// ---------------- launch ----------------
extern "C" void kernel_launch(void* const* d_in, const int* in_sizes, int n_in,
                              void* d_out, int out_size, void* d_ws, size_t ws_size,
                              hipStream_t stream) {
    const float* x    = (const float*)d_in[0];
    const int*   ei   = (const int*)d_in[1];
    const int*   src  = ei;
    const int*   dst  = ei + NE;
    const float* W1   = (const float*)d_in[2];
    const float* b1   = (const float*)d_in[3];
    const float* g1   = (const float*)d_in[4];
    const float* be1  = (const float*)d_in[5];
    const float* W2   = (const float*)d_in[6];
    const float* b2   = (const float*)d_in[7];
    const float* g2   = (const float*)d_in[8];
    const float* be2  = (const float*)d_in[9];
    const float* W3   = (const float*)d_in[10];
    const float* b3   = (const float*)d_in[11];
    const float* We1  = (const float*)d_in[12];
    const float* bme1 = (const float*)d_in[13];
    const float* We2  = (const float*)d_in[14];
    const float* bme2 = (const float*)d_in[15];
    const float* We3  = (const float*)d_in[16];
    const float* bme3 = (const float*)d_in[17];
    float* out = (float*)d_out;
    char* ws = (char*)d_ws;

    float* dsq      = (float*)ws;                         ws += NPAD * 4;
    float* stats    = (float*)ws;                         ws += 1024 * 4;
    int*   cnt      = (int*)ws;                           ws += NPAD * 4;
    int*   cursor   = (int*)ws;                           ws += NPAD * 4;
    int*   bsum     = (int*)ws;                           ws += 256 * 4;
    int*   row_start= (int*)ws;                           ws += (NPAD + 16) * 4;
    unsigned short* pk2 = (unsigned short*)ws;            ws += (size_t)NE * 2;
    ws += 64;  // alignment pad
    unsigned short* bufHb = (unsigned short*)ws;          ws += (size_t)NN * 256 * 2;
    float* bufO     = (float*)ws;                         ws += (size_t)NN * 256 * 4;

    const int nblkE = (NE + 255) / 256;
    const int nblkNode = (NN + 3) / 4;
    const int gy = (NN + 127) / 128;   // 391

    // ---- CSR build + degree terms ----
    hipMemsetAsync(cnt, 0, NPAD * sizeof(int), stream);
    k_count_int<<<nblkE, 256, 0, stream>>>(dst, cnt);
    k_bsum<<<SCAN_BLOCKS, 256, 0, stream>>>(cnt, bsum);
    k_scan_bsum<<<1, 256, 0, stream>>>(bsum);
    k_scan_fin<<<SCAN_BLOCKS, 256, 0, stream>>>(cnt, bsum, row_start, cursor, dsq);
    k_fill<<<nblkE, 256, 0, stream>>>(src, dst, cursor, pk2);

    // ---- layer 1: 256 -> 256 MFMA (bf16+dsq-scaled out), agg, BN stats ----
    k_gemm_mfma<128, false, true><<<dim3(2, gy), 256, 0, stream>>>(
        x, W1, bufHb, NN, 256, 256, nullptr, nullptr, nullptr, dsq);
    k_agg256_b<<<nblkNode, 256, 0, stream>>>(bufHb, row_start, pk2, dsq, b1, bufO);
    hipMemsetAsync(stats, 0, 1024 * sizeof(float), stream);
    k_bn_stats<256><<<256, 256, 0, stream>>>(bufO, stats);
    k_bn_fin<<<1, 256, 0, stream>>>(stats, 256);

    // ---- layer 2: A = BN1(bufO) fused; 256 -> 64 MFMA; agg; BN2 stats ----
    k_gemm_mfma<64, true, true><<<dim3(1, gy), 256, 0, stream>>>(
        bufO, W2, bufHb, NN, 256, 64, stats, g1, be1, dsq);
    k_agg64_b<false><<<nblkNode, 256, 0, stream>>>(bufHb, row_start, pk2, dsq, b2, bufO);
    hipMemsetAsync(stats, 0, 1024 * sizeof(float), stream);
    k_bn_stats<64><<<256, 256, 0, stream>>>(bufO, stats);
    k_bn_fin<<<1, 256, 0, stream>>>(stats, 64);

    // ---- layer 3: A = BN2(bufO) fused; 64 -> 64 MFMA; agg + relu ----
    k_gemm_mfma<64, true, true><<<dim3(1, gy), 256, 0, stream>>>(
        bufO, W3, bufHb, NN, 64, 64, stats, g2, be2, dsq);
    k_agg64_b<true><<<nblkNode, 256, 0, stream>>>(bufHb, row_start, pk2, dsq, b3, bufO);

    // ---- layer 4: 64 -> 64 MFMA (same W3/b3, no relu) -> emb in bufO ----
    k_gemm_mfma<64, false, true><<<dim3(1, gy), 256, 0, stream>>>(
        bufO, W3, bufHb, NN, 64, 64, nullptr, nullptr, nullptr, dsq);
    k_agg64_b<false><<<nblkNode, 256, 0, stream>>>(bufHb, row_start, pk2, dsq, b3, bufO);

    // ---- edge MLP: fused A|B gemm -> AB[NN][128] bf16, then MLP ----
    unsigned short* ABbuf = bufHb;   // NN*128 ushort
    k_gemm_mfma<128, false, false, true><<<dim3(1, gy), 256, 0, stream>>>(
        bufO, We1, ABbuf, NN, 64, 128, nullptr, nullptr, nullptr, nullptr);
    k_edge_mlp5<<<(NE + EB - 1) / EB, EB, 0, stream>>>(ABbuf, src, dst, bme1, We2, bme2, We3, bme3, out);

    (void)in_sizes; (void)n_in; (void)out_size; (void)ws_size;
}